// Round 6
// baseline (811.085 us; speedup 1.0000x reference)
//
#include <hip/hip_runtime.h>

typedef unsigned short u16;
typedef __bf16 bf16_t;
typedef bf16_t bf16x8 __attribute__((ext_vector_type(8)));
typedef float f32x4 __attribute__((ext_vector_type(4)));

__device__ __forceinline__ u16 f2b(float f) {
  union { float f; unsigned u; } v; v.f = f;
  unsigned r = (v.u + 0x7fffu + ((v.u >> 16) & 1u)) >> 16;
  return (u16)r;
}
__device__ __forceinline__ float b2f(u16 b) {
  union { unsigned u; float f; } v; v.u = ((unsigned)b) << 16;
  return v.f;
}
__device__ __forceinline__ f32x4 mfma16(bf16x8 a, bf16x8 b, f32x4 c) {
  return __builtin_amdgcn_mfma_f32_16x16x32_bf16(a, b, c, 0, 0, 0);
}

// ---------------- K0: fp32 -> bf16 weight conversion ----------------
struct CvtJobs {
  const float* s[8];
  u16* d[8];
  int n[8];
};
__global__ void k0_cvt(CvtJobs j) {
  int job = blockIdx.y;
  const float* s = j.s[job];
  u16* d = j.d[job];
  int n = j.n[job];
  int stride = gridDim.x * blockDim.x * 4;
  for (int i = (blockIdx.x * blockDim.x + threadIdx.x) * 4; i < n; i += stride) {
    float4 v = *(const float4*)(s + i);
    ushort4 o4;
    o4.x = f2b(v.x); o4.y = f2b(v.y); o4.z = f2b(v.z); o4.w = f2b(v.w);
    *(ushort4*)(d + i) = o4;
  }
}

#define LW 392   // xs_b row pitch (u16)
#define TW 40    // xs_t / Bs row pitch
#define AW 40    // attn row pitch

// ---------------- K1: h-path full mix (+psum_yh, psum_x); w-path pool-only OR full mix (wmode) ----------------
__global__ __launch_bounds__(256, 2) void k1_mixer(
    const float* __restrict__ x,
    const u16* __restrict__ Wc_h_b, const float* __restrict__ bc_h,
    const u16* __restrict__ Wg_h_b, const float* __restrict__ bg_h,
    const u16* __restrict__ Wc_w_b, const float* __restrict__ bc_w,
    const u16* __restrict__ Wg_w_b, const float* __restrict__ bg_w,
    u16* __restrict__ y_h, u16* __restrict__ y_w, int wmode,
    float* __restrict__ psum_yh, float* __restrict__ psum_yw,
    float* __restrict__ psum_x)
{
  __shared__ u16 xs_b[32 * LW];     // x rows [l][c] bf16; later y tile [j][c]
  __shared__ u16 xs_t[384 * TW];    // transposed [c][l]
  __shared__ u16 attn[8 * 32 * AW]; // [h][j][l]
  __shared__ u16 whead[16 * 72];    // [h pad16][k=64]
  __shared__ float rs[8 * 32];      // [h][l] attn row-sums (pool-only path)

  const int tid = threadIdx.x;
  const int bid = blockIdx.x;
  const int path = bid >> 11;
  const int n = bid & 2047;
  const int b = n >> 5, o = n & 31;
  long base; int strideL;
  if (path == 0) { base = (long)b * 393216 + (long)o * 384;   strideL = 12288; }
  else           { base = (long)b * 393216 + (long)o * 12288; strideL = 384; }
  const float* xseq = x + base;

  const u16* Wc_b = path ? Wc_w_b : Wc_h_b;
  const float* bc = path ? bc_w : bc_h;
  const u16* Wg_b = path ? Wg_w_b : Wg_h_b;
  const float* bg = path ? bg_w : bg_h;
  const int domix = (path == 0) || wmode;

  // ---- load x-seq -> xs_b bf16 ----
  for (int i = tid; i < 3072; i += 256) {
    int l = i / 96, c4 = (i % 96) * 4;
    float4 v = *(const float4*)(xseq + (long)l * strideL + c4);
    ushort4 w4;
    w4.x = f2b(v.x); w4.y = f2b(v.y); w4.z = f2b(v.z); w4.w = f2b(v.w);
    *(ushort4*)&xs_b[l * LW + c4] = w4;
  }
  for (int i = tid; i < 576; i += 256) whead[576 + i] = 0;
  __syncthreads();

  if (domix) {
    // transpose for the mix A-operand
    for (int i = tid; i < 3072; i += 256) {
      int c = i % 384, l4 = (i / 384) * 4;
      ushort4 w4;
      w4.x = xs_b[(l4 + 0) * LW + c];
      w4.y = xs_b[(l4 + 1) * LW + c];
      w4.z = xs_b[(l4 + 2) * LW + c];
      w4.w = xs_b[(l4 + 3) * LW + c];
      *(ushort4*)&xs_t[c * TW + l4] = w4;
    }
  }
  if (path == 0) {
    // per-seq x column sums (deterministic psum slot)
    for (int c = tid; c < 384; c += 256) {
      float s = 0.f;
      for (int l = 0; l < 32; l++) s += b2f(xs_b[l * LW + c]);
      psum_x[(long)n * 384 + c] = s;
    }
  }

  const int wave = tid >> 6, lane = tid & 63;
  const int lq = lane >> 4, lr = lane & 15;
  const f32x4 z = {0.f, 0.f, 0.f, 0.f};

  // ---- compress ----
  if (wave < 2) {
    f32x4 acc = z;
    for (int ks = 0; ks < 12; ks++) {
      bf16x8 af  = *(const bf16x8*)&xs_b[(wave * 16 + lr) * LW + ks * 32 + lq * 8];
      bf16x8 bfr = *(const bf16x8*)(Wc_b + lr * 384 + ks * 32 + lq * 8);
      acc = mfma16(af, bfr, acc);
    }
    float bcv = bc[lr];
    for (int r = 0; r < 4; r++) {
      int l = wave * 16 + lq * 4 + r;
      whead[(lr >> 1) * 72 + l * 2 + (lr & 1)] = f2b(acc[r] + bcv);
    }
  }
  __syncthreads();

  // ---- generate ----
  {
    bf16x8 ga0 = *(const bf16x8*)&whead[lr * 72 + lq * 8];
    bf16x8 ga1 = *(const bf16x8*)&whead[lr * 72 + 32 + lq * 8];
    for (int t = 0; t < 16; t++) {
      int nt = wave * 16 + t;
      const u16* wg = Wg_b + (nt * 16 + lr) * 64;
      bf16x8 gb0 = *(const bf16x8*)(wg + lq * 8);
      bf16x8 gb1 = *(const bf16x8*)(wg + 32 + lq * 8);
      f32x4 acc = z;
      acc = mfma16(ga0, gb0, acc);
      acc = mfma16(ga1, gb1, acc);
      if (lq < 2) {
        int m = nt * 16 + lr, ii = m >> 5, jj = m & 31;
        for (int r = 0; r < 4; r++)
          attn[((lq * 4 + r) * 32 + jj) * AW + ii] = f2b(acc[r]);
      }
    }
  }
  __syncthreads();

  // ---- softmax over l per (h, j) ----
  {
    int h = tid >> 5, j = tid & 31;
    u16* row = &attn[(h * 32 + j) * AW];
    float v[32]; float mx = -1e30f;
    for (int i = 0; i < 32; i++) {
      v[i] = b2f(row[i]) + bg[i * 32 + j];
      mx = fmaxf(mx, v[i]);
    }
    float s = 0.f;
    for (int i = 0; i < 32; i++) { v[i] = __expf(v[i] - mx); s += v[i]; }
    float inv = 1.0f / s;
    for (int i = 0; i < 32; i++) row[i] = f2b(v[i] * inv);
  }
  __syncthreads();

  if (domix) {
    // ---- mix: y[j][c] ----
    for (int hh = 0; hh < 2; hh++) {
      int h = wave * 2 + hh;
      bf16x8 bf0 = *(const bf16x8*)&attn[(h * 32 + lr) * AW + lq * 8];
      bf16x8 bf1 = *(const bf16x8*)&attn[(h * 32 + 16 + lr) * AW + lq * 8];
      for (int mt = 0; mt < 3; mt++) {
        bf16x8 af = *(const bf16x8*)&xs_t[(h * 48 + mt * 16 + lr) * TW + lq * 8];
        f32x4 a0 = mfma16(af, bf0, z);
        f32x4 a1 = mfma16(af, bf1, z);
        for (int r = 0; r < 4; r++) {
          int c = h * 48 + mt * 16 + lq * 4 + r;
          xs_b[lr * LW + c]        = f2b(a0[r]);
          xs_b[(16 + lr) * LW + c] = f2b(a1[r]);
        }
      }
    }
    __syncthreads();
    // store y + per-seq column sums
    if (path == 0) {
      u16* yout = y_h + base;   // token t = b*1024 + l*32 + o, at t*384
      for (int i = tid; i < 1536; i += 256) {
        int l = i / 48, uu = (i % 48) * 8;
        *(uint4*)(yout + (long)l * 12288 + uu) = *(const uint4*)&xs_b[l * LW + uu];
      }
    } else {
      u16* yout = y_w + (long)n * 12288;  // token t = n*32 + l (contiguous)
      for (int i = tid; i < 1536; i += 256) {
        int l = i / 48, uu = (i % 48) * 8;
        *(uint4*)(yout + (long)l * 384 + uu) = *(const uint4*)&xs_b[l * LW + uu];
      }
    }
    float* pdst = (path ? psum_yw : psum_yh) + (long)n * 384;
    for (int c = tid; c < 384; c += 256) {
      float s = 0.f;
      for (int jj = 0; jj < 32; jj++) s += b2f(xs_b[jj * LW + c]);
      pdst[c] = s;
    }
  } else {
    // ---- pool-only: sum_j y[j][c] = sum_l xs[l][c] * rs[h(c)][l] ----
    {
      int h = tid >> 5, l = tid & 31;
      float s = 0.f;
      for (int j = 0; j < 32; j++) s += b2f(attn[(h * 32 + j) * AW + l]);
      rs[h * 32 + l] = s;
    }
    __syncthreads();
    for (int c = tid; c < 384; c += 256) {
      int h = c / 48;
      float s = 0.f;
      for (int l = 0; l < 32; l++) s += b2f(xs_b[l * LW + c]) * rs[h * 32 + l];
      psum_yw[(long)n * 384 + c] = s;
    }
  }
}

// ---------------- K3: psums -> reweighting scales ----------------
__global__ __launch_bounds__(384) void k3_scales(
    const float* __restrict__ psum_yh, const float* __restrict__ psum_yw,
    const float* __restrict__ psum_x,
    const float* __restrict__ Wo_h, const float* __restrict__ bo_h,
    const float* __restrict__ Wo_w, const float* __restrict__ bo_w,
    const float* __restrict__ Wmlpc,
    const float* __restrict__ Wr1, const float* __restrict__ br1,
    const float* __restrict__ Wr2, const float* __restrict__ br2,
    float* __restrict__ scal)
{
  __shared__ float ph[384], pw[384], px[384], a[384], r1[96];
  int b = blockIdx.x, t = threadIdx.x;
  float sh = 0.f, sw = 0.f, sx = 0.f;
  for (int o = 0; o < 32; o++) {
    sh += psum_yh[(long)(b * 32 + o) * 384 + t];
    sw += psum_yw[(long)(b * 32 + o) * 384 + t];
    sx += psum_x[(long)(b * 32 + o) * 384 + t];
  }
  ph[t] = sh; pw[t] = sw; px[t] = sx;
  __syncthreads();
  float s1 = 0.f, s2 = 0.f, s3 = 0.f;
  for (int k = 0; k < 384; k++) {
    s1 += ph[k] * Wo_h[t * 384 + k];
    s2 += pw[k] * Wo_w[t * 384 + k];
    s3 += px[k] * Wmlpc[t * 384 + k];
  }
  a[t] = (s1 + s2 + s3) * (1.f / 1024.f) + bo_h[t] + bo_w[t];
  __syncthreads();
  if (t < 96) {
    float s = 0.f;
    for (int k = 0; k < 384; k++) s += a[k] * Wr1[t * 384 + k];
    s += br1[t];
    r1[t] = s * 0.5f * (1.f + erff(s * 0.70710678118654752f));
  }
  __syncthreads();
  {
    float sv[3];
    for (int si = 0; si < 3; si++) {
      float acc = 0.f;
      for (int k = 0; k < 96; k++) acc += r1[k] * Wr2[(t * 3 + si) * 96 + k];
      sv[si] = acc + br2[t * 3 + si];
    }
    float mx = fmaxf(sv[0], fmaxf(sv[1], sv[2]));
    float e0 = __expf(sv[0] - mx), e1 = __expf(sv[1] - mx), e2 = __expf(sv[2] - mx);
    float inv = 1.f / (e0 + e1 + e2);
    scal[0 * 24576 + b * 384 + t] = e0 * inv;   // h
    scal[1 * 24576 + b * 384 + t] = e1 * inv;   // w
    scal[2 * 24576 + b * 384 + t] = e2 * inv;   // c
  }
}

// ---- barrier-free GEMM, 128-row tile: acc += bufA @ Bglob^T ----
__device__ __forceinline__ void gemm128(
    const u16* __restrict__ Bglob, const u16* __restrict__ bufA,
    f32x4 acc[4][6], int wm, int wn, int lq, int lr)
{
  const u16* bp0 = Bglob + (wn * 96 + lr) * 384 + lq * 8;
  const u16* ap0 = bufA + (wm * 64 + lr) * 392 + lq * 8;
  bf16x8 bcur[6], af[4];
#pragma unroll
  for (int nt = 0; nt < 6; nt++) bcur[nt] = *(const bf16x8*)(bp0 + nt * 6144);
#pragma unroll
  for (int mt = 0; mt < 4; mt++) af[mt] = *(const bf16x8*)(ap0 + mt * 6272);
  for (int ks = 0; ks < 12; ks++) {
    bf16x8 bnx[6], an[4];
    const int k1 = (ks < 11 ? ks + 1 : 11) * 32;
#pragma unroll
    for (int nt = 0; nt < 6; nt++) bnx[nt] = *(const bf16x8*)(bp0 + nt * 6144 + k1);
#pragma unroll
    for (int mt = 0; mt < 4; mt++) an[mt] = *(const bf16x8*)(ap0 + mt * 6272 + k1);
#pragma unroll
    for (int nt = 0; nt < 6; nt++)
#pragma unroll
      for (int mt = 0; mt < 4; mt++)
        acc[mt][nt] = mfma16(af[mt], bcur[nt], acc[mt][nt]);
#pragma unroll
    for (int nt = 0; nt < 6; nt++) bcur[nt] = bnx[nt];
#pragma unroll
    for (int mt = 0; mt < 4; mt++) af[mt] = an[mt];
  }
}

// ---- barrier-free GEMM, 64-row tile ----
__device__ __forceinline__ void gemm64(
    const u16* __restrict__ Bglob, const u16* __restrict__ bufA,
    f32x4 acc[2][6], int wm, int wn, int lq, int lr)
{
  const u16* bp0 = Bglob + (wn * 96 + lr) * 384 + lq * 8;
  const u16* ap0 = bufA + (wm * 32 + lr) * 392 + lq * 8;
  bf16x8 bcur[6], af[2];
#pragma unroll
  for (int nt = 0; nt < 6; nt++) bcur[nt] = *(const bf16x8*)(bp0 + nt * 6144);
#pragma unroll
  for (int mt = 0; mt < 2; mt++) af[mt] = *(const bf16x8*)(ap0 + mt * 6272);
  for (int ks = 0; ks < 12; ks++) {
    bf16x8 bnx[6], an[2];
    const int k1 = (ks < 11 ? ks + 1 : 11) * 32;
#pragma unroll
    for (int nt = 0; nt < 6; nt++) bnx[nt] = *(const bf16x8*)(bp0 + nt * 6144 + k1);
#pragma unroll
    for (int mt = 0; mt < 2; mt++) an[mt] = *(const bf16x8*)(ap0 + mt * 6272 + k1);
#pragma unroll
    for (int nt = 0; nt < 6; nt++)
#pragma unroll
      for (int mt = 0; mt < 2; mt++)
        acc[mt][nt] = mfma16(af[mt], bcur[nt], acc[mt][nt]);
#pragma unroll
    for (int nt = 0; nt < 6; nt++) bcur[nt] = bnx[nt];
#pragma unroll
    for (int mt = 0; mt < 2; mt++) af[mt] = an[mt];
  }
}

// ---------------- K24-B: x-stage + c-GEMM + w-recompute + w/h GEMMs + Wp (small-ws fallback) ----------------
// Exact R2 known-good version (253 us).
__global__ __launch_bounds__(512, 2) void k24_final_B(
    const float* __restrict__ x, const u16* __restrict__ y_h,
    const u16* __restrict__ Wc_w_b, const float* __restrict__ bc_w,
    const u16* __restrict__ Wg_w_b, const float* __restrict__ bg_w,
    const u16* __restrict__ Wo_h_b, const u16* __restrict__ Wo_w_b,
    const u16* __restrict__ Wmlpc_b, const u16* __restrict__ Wp_b,
    const float* __restrict__ bo_h, const float* __restrict__ bo_w,
    const float* __restrict__ bp,
    const float* __restrict__ scal, float* __restrict__ out)
{
  __shared__ u16 bufA[128 * 392];
  __shared__ u16 Bs[384 * 40];
  __shared__ u16 attn[8 * 32 * AW];
  __shared__ u16 whead[16 * 72];

  const int tid = threadIdx.x;
  const int m0 = blockIdx.x * 128;
  const int b = m0 >> 10;
  const int wave = tid >> 6, lane = tid & 63;
  const int lq = lane >> 4, lr = lane & 15;
  const int wm = wave >> 2, wn = wave & 3;
  const f32x4 z = {0.f, 0.f, 0.f, 0.f};

  for (int i = tid; i < 12288; i += 512) {
    int row = i / 96, c4 = (i % 96) * 4;
    float4 v = *(const float4*)(x + (long)(m0 + row) * 384 + c4);
    ushort4 w4;
    w4.x = f2b(v.x); w4.y = f2b(v.y); w4.z = f2b(v.z); w4.w = f2b(v.w);
    *(ushort4*)&bufA[row * 392 + c4] = w4;
  }
  for (int i = tid; i < 576; i += 512) whead[576 + i] = 0;
  __syncthreads();

  f32x4 acc[4][6];
#pragma unroll
  for (int i = 0; i < 4; i++)
#pragma unroll
    for (int jn = 0; jn < 6; jn++) acc[i][jn] = z;

  gemm128(Wmlpc_b, bufA, acc, wm, wn, lq, lr);
  {
    const float* s2p = scal + 2 * 24576 + b * 384;
    const float* s1p = scal + 1 * 24576 + b * 384;
#pragma unroll
    for (int nt = 0; nt < 6; nt++) {
      int col = wn * 96 + nt * 16 + lr;
      float r = s2p[col] / fmaxf(s1p[col], 1e-30f);
#pragma unroll
      for (int mt = 0; mt < 4; mt++)
#pragma unroll
        for (int rr = 0; rr < 4; rr++) acc[mt][nt][rr] *= r;
    }
  }

  for (int q = 0; q < 4; q++) {
    for (int i = tid; i < 3072; i += 512) {
      int c = i % 384, l4 = (i / 384) * 4;
      ushort4 w4;
      w4.x = bufA[(q * 32 + l4 + 0) * 392 + c];
      w4.y = bufA[(q * 32 + l4 + 1) * 392 + c];
      w4.z = bufA[(q * 32 + l4 + 2) * 392 + c];
      w4.w = bufA[(q * 32 + l4 + 3) * 392 + c];
      *(ushort4*)&Bs[c * 40 + l4] = w4;
    }
    if (wave < 2) {
      f32x4 ac = z;
      for (int ks = 0; ks < 12; ks++) {
        bf16x8 afg = *(const bf16x8*)&bufA[(q * 32 + wave * 16 + lr) * 392 + ks * 32 + lq * 8];
        bf16x8 bfg = *(const bf16x8*)(Wc_w_b + lr * 384 + ks * 32 + lq * 8);
        ac = mfma16(afg, bfg, ac);
      }
      float bcv = bc_w[lr];
      for (int r = 0; r < 4; r++) {
        int l = wave * 16 + lq * 4 + r;
        whead[(lr >> 1) * 72 + l * 2 + (lr & 1)] = f2b(ac[r] + bcv);
      }
    }
    __syncthreads();
    {
      bf16x8 ga0 = *(const bf16x8*)&whead[lr * 72 + lq * 8];
      bf16x8 ga1 = *(const bf16x8*)&whead[lr * 72 + 32 + lq * 8];
      for (int t = 0; t < 8; t++) {
        int nt = wave * 8 + t;
        const u16* wg = Wg_w_b + (nt * 16 + lr) * 64;
        bf16x8 gb0 = *(const bf16x8*)(wg + lq * 8);
        bf16x8 gb1 = *(const bf16x8*)(wg + 32 + lq * 8);
        f32x4 ac = z;
        ac = mfma16(ga0, gb0, ac);
        ac = mfma16(ga1, gb1, ac);
        if (lq < 2) {
          int m = nt * 16 + lr, ii = m >> 5, jj = m & 31;
          for (int r = 0; r < 4; r++)
            attn[((lq * 4 + r) * 32 + jj) * AW + ii] = f2b(ac[r]);
        }
      }
    }
    __syncthreads();
    if (tid < 256) {
      int h = tid >> 5, j = tid & 31;
      u16* row = &attn[(h * 32 + j) * AW];
      float v[32]; float mx = -1e30f;
      for (int i = 0; i < 32; i++) {
        v[i] = b2f(row[i]) + bg_w[i * 32 + j];
        mx = fmaxf(mx, v[i]);
      }
      float s = 0.f;
      for (int i = 0; i < 32; i++) { v[i] = __expf(v[i] - mx); s += v[i]; }
      float inv = 1.0f / s;
      for (int i = 0; i < 32; i++) row[i] = f2b(v[i] * inv);
    }
    __syncthreads();
    {
      int h = wave;
      bf16x8 bf0 = *(const bf16x8*)&attn[(h * 32 + lr) * AW + lq * 8];
      bf16x8 bf1 = *(const bf16x8*)&attn[(h * 32 + 16 + lr) * AW + lq * 8];
      for (int mt = 0; mt < 3; mt++) {
        bf16x8 afg = *(const bf16x8*)&Bs[(h * 48 + mt * 16 + lr) * 40 + lq * 8];
        f32x4 a0 = mfma16(afg, bf0, z);
        f32x4 a1 = mfma16(afg, bf1, z);
        for (int r = 0; r < 4; r++) {
          int c = h * 48 + mt * 16 + lq * 4 + r;
          bufA[(q * 32 + lr) * 392 + c]      = f2b(a0[r]);
          bufA[(q * 32 + 16 + lr) * 392 + c] = f2b(a1[r]);
        }
      }
    }
    __syncthreads();
  }

  gemm128(Wo_w_b, bufA, acc, wm, wn, lq, lr);
  {
    const float* s1p = scal + 1 * 24576 + b * 384;
    const float* s0p = scal + 0 * 24576 + b * 384;
#pragma unroll
    for (int nt = 0; nt < 6; nt++) {
      int col = wn * 96 + nt * 16 + lr;
      float r = s1p[col] / fmaxf(s0p[col], 1e-30f);
#pragma unroll
      for (int mt = 0; mt < 4; mt++)
#pragma unroll
        for (int rr = 0; rr < 4; rr++) acc[mt][nt][rr] *= r;
    }
  }
  __syncthreads();

  for (int i = tid; i < 6144; i += 512) {
    int row = i / 48, u8 = (i % 48) * 8;
    *(uint4*)&bufA[row * 392 + u8] = *(const uint4*)(y_h + (long)(m0 + row) * 384 + u8);
  }
  __syncthreads();
  gemm128(Wo_h_b, bufA, acc, wm, wn, lq, lr);
  __syncthreads();

  {
    const float* s0p = scal + 0 * 24576 + b * 384;
    const float* s1p = scal + 1 * 24576 + b * 384;
#pragma unroll
    for (int nt = 0; nt < 6; nt++) {
      int col = wn * 96 + nt * 16 + lr;
      float s0v = s0p[col];
      float bcb = s0v * bo_h[col] + s1p[col] * bo_w[col];
#pragma unroll
      for (int mt = 0; mt < 4; mt++)
#pragma unroll
        for (int r = 0; r < 4; r++) {
          int row = wm * 64 + mt * 16 + lq * 4 + r;
          bufA[row * 392 + col] = f2b(acc[mt][nt][r] * s0v + bcb);
        }
    }
  }
  __syncthreads();

#pragma unroll
  for (int i = 0; i < 4; i++)
#pragma unroll
    for (int jn = 0; jn < 6; jn++) acc[i][jn] = z;
  gemm128(Wp_b, bufA, acc, wm, wn, lq, lr);
#pragma unroll
  for (int nt = 0; nt < 6; nt++) {
    int col = wn * 96 + nt * 16 + lr;
    float bi = bp[col];
#pragma unroll
    for (int mt = 0; mt < 4; mt++)
#pragma unroll
      for (int r = 0; r < 4; r++) {
        int row = m0 + wm * 64 + mt * 16 + lq * 4 + r;
        out[(long)row * 384 + col] = acc[mt][nt][r] + bi;
      }
  }
}

// ---------------- K24-A: pure GEMM chain, 64-row tiles (big ws) ----------------
// grid 1024, LDS = bufA (50 KB), launch_bounds(512,6) caps VGPR so ~3 blocks/CU
// co-reside (R3 measured 58% occupancy with this shape). Plain staging loops —
// TLP hides latency; NO register preloads (R5 showed they halve occupancy).
__global__ __launch_bounds__(512, 6) void k24_final_A(
    const float* __restrict__ x,
    const u16* __restrict__ y_h, const u16* __restrict__ y_w,
    const u16* __restrict__ Wo_h_b, const u16* __restrict__ Wo_w_b,
    const u16* __restrict__ Wmlpc_b, const u16* __restrict__ Wp_b,
    const float* __restrict__ bo_h, const float* __restrict__ bo_w,
    const float* __restrict__ bp,
    const float* __restrict__ scal, float* __restrict__ out)
{
  __shared__ u16 bufA[64 * 392];

  const int tid = threadIdx.x;
  const int m0 = blockIdx.x * 64;
  const int b = m0 >> 10;
  const int wave = tid >> 6, lane = tid & 63;
  const int lq = lane >> 4, lr = lane & 15;
  const int wm = wave >> 2, wn = wave & 3;
  const f32x4 z = {0.f, 0.f, 0.f, 0.f};

  // stage x fp32 -> bufA bf16
  for (int i = tid; i < 6144; i += 512) {
    int row = i / 96, c4 = (i % 96) * 4;
    float4 v = *(const float4*)(x + (long)(m0 + row) * 384 + c4);
    ushort4 w4;
    w4.x = f2b(v.x); w4.y = f2b(v.y); w4.z = f2b(v.z); w4.w = f2b(v.w);
    *(ushort4*)&bufA[row * 392 + c4] = w4;
  }
  __syncthreads();

  f32x4 acc[2][6];
#pragma unroll
  for (int i = 0; i < 2; i++)
#pragma unroll
    for (int jn = 0; jn < 6; jn++) acc[i][jn] = z;

  // src = c: acc = T_c
  gemm64(Wmlpc_b, bufA, acc, wm, wn, lq, lr);
  {
    const float* s2p = scal + 2 * 24576 + b * 384;
    const float* s1p = scal + 1 * 24576 + b * 384;
#pragma unroll
    for (int nt = 0; nt < 6; nt++) {
      int col = wn * 96 + nt * 16 + lr;
      float r = s2p[col] / fmaxf(s1p[col], 1e-30f);
#pragma unroll
      for (int mt = 0; mt < 2; mt++)
#pragma unroll
        for (int rr = 0; rr < 4; rr++) acc[mt][nt][rr] *= r;
    }
  }
  __syncthreads();   // all bufA reads done

  // stage y_w (ws, token-major pitch 384 u16)
  for (int i = tid; i < 3072; i += 512) {
    int row = i / 48, u8 = (i % 48) * 8;
    *(uint4*)&bufA[row * 392 + u8] = *(const uint4*)(y_w + (long)(m0 + row) * 384 + u8);
  }
  __syncthreads();

  // src = w: acc += T_w
  gemm64(Wo_w_b, bufA, acc, wm, wn, lq, lr);
  {
    const float* s1p = scal + 1 * 24576 + b * 384;
    const float* s0p = scal + 0 * 24576 + b * 384;
#pragma unroll
    for (int nt = 0; nt < 6; nt++) {
      int col = wn * 96 + nt * 16 + lr;
      float r = s1p[col] / fmaxf(s0p[col], 1e-30f);
#pragma unroll
      for (int mt = 0; mt < 2; mt++)
#pragma unroll
        for (int rr = 0; rr < 4; rr++) acc[mt][nt][rr] *= r;
    }
  }
  __syncthreads();   // all bufA reads done

  // stage y_h
  for (int i = tid; i < 3072; i += 512) {
    int row = i / 48, u8 = (i % 48) * 8;
    *(uint4*)&bufA[row * 392 + u8] = *(const uint4*)(y_h + (long)(m0 + row) * 384 + u8);
  }
  __syncthreads();

  // src = h: acc += T_h
  gemm64(Wo_h_b, bufA, acc, wm, wn, lq, lr);
  __syncthreads();   // all bufA reads done before comb dump

  // comb = acc*s0 + s0*bo_h + s1*bo_w -> bufA bf16
  {
    const float* s0p = scal + 0 * 24576 + b * 384;
    const float* s1p = scal + 1 * 24576 + b * 384;
#pragma unroll
    for (int nt = 0; nt < 6; nt++) {
      int col = wn * 96 + nt * 16 + lr;
      float s0v = s0p[col];
      float bcb = s0v * bo_h[col] + s1p[col] * bo_w[col];
#pragma unroll
      for (int mt = 0; mt < 2; mt++)
#pragma unroll
        for (int r = 0; r < 4; r++) {
          int row = wm * 32 + mt * 16 + lq * 4 + r;
          bufA[row * 392 + col] = f2b(acc[mt][nt][r] * s0v + bcb);
        }
    }
  }
  __syncthreads();

  // out = comb @ Wp^T + bp
#pragma unroll
  for (int i = 0; i < 2; i++)
#pragma unroll
    for (int jn = 0; jn < 6; jn++) acc[i][jn] = z;
  gemm64(Wp_b, bufA, acc, wm, wn, lq, lr);
#pragma unroll
  for (int nt = 0; nt < 6; nt++) {
    int col = wn * 96 + nt * 16 + lr;
    float bi = bp[col];
#pragma unroll
    for (int mt = 0; mt < 2; mt++)
#pragma unroll
      for (int r = 0; r < 4; r++) {
        int row = m0 + wm * 32 + mt * 16 + lq * 4 + r;
        out[(long)row * 384 + col] = acc[mt][nt][r] + bi;
      }
  }
}

// ---------------- host ----------------
extern "C" void kernel_launch(void* const* d_in, const int* in_sizes, int n_in,
                              void* d_out, int out_size, void* d_ws, size_t ws_size,
                              hipStream_t stream) {
  const float* x     = (const float*)d_in[0];
  const float* Wc_h  = (const float*)d_in[1];
  const float* bc_h  = (const float*)d_in[2];
  const float* Wg_h  = (const float*)d_in[3];
  const float* bg_h  = (const float*)d_in[4];
  const float* Wo_h  = (const float*)d_in[5];
  const float* bo_h  = (const float*)d_in[6];
  const float* Wc_w  = (const float*)d_in[7];
  const float* bc_w  = (const float*)d_in[8];
  const float* Wg_w  = (const float*)d_in[9];
  const float* bg_w  = (const float*)d_in[10];
  const float* Wo_w  = (const float*)d_in[11];
  const float* bo_w  = (const float*)d_in[12];
  const float* Wmlpc = (const float*)d_in[13];
  const float* Wr1   = (const float*)d_in[14];
  const float* br1   = (const float*)d_in[15];
  const float* Wr2   = (const float*)d_in[16];
  const float* br2   = (const float*)d_in[17];
  const float* Wp    = (const float*)d_in[18];
  const float* bp    = (const float*)d_in[19];
  float* out = (float*)d_out;

  // base workspace layout: 61,530,112 bytes
  char* ws = (char*)d_ws;
  u16* y_h       = (u16*)(ws + 0);          // 50,331,648
  float* psum_yh = (float*)(ws + 50331648); //  3,145,728
  float* psum_yw = (float*)(ws + 53477376); //  3,145,728
  float* psum_x  = (float*)(ws + 56623104); //  3,145,728
  float* scal    = (float*)(ws + 59768832); //    294,912
  u16* Wc_h_b    = (u16*)(ws + 60063744);
  u16* Wc_w_b    = (u16*)(ws + 60076032);
  u16* Wg_h_b    = (u16*)(ws + 60088320);
  u16* Wg_w_b    = (u16*)(ws + 60219392);
  u16* Wo_h_b    = (u16*)(ws + 60350464);
  u16* Wo_w_b    = (u16*)(ws + 60645376);
  u16* Wmlpc_b   = (u16*)(ws + 60940288);
  u16* Wp_b      = (u16*)(ws + 61235200);

  // optional y_w region if the workspace is large enough
  const size_t NEED_BIG = 61530112ULL + 50331648ULL;
  int wmode = (ws_size >= NEED_BIG) ? 1 : 0;
  u16* y_w = wmode ? (u16*)(ws + 61530112) : (u16*)(ws + 0) /*unused*/;

  CvtJobs jobs;
  jobs.s[0] = Wc_h;  jobs.d[0] = Wc_h_b;  jobs.n[0] = 6144;
  jobs.s[1] = Wc_w;  jobs.d[1] = Wc_w_b;  jobs.n[1] = 6144;
  jobs.s[2] = Wg_h;  jobs.d[2] = Wg_h_b;  jobs.n[2] = 65536;
  jobs.s[3] = Wg_w;  jobs.d[3] = Wg_w_b;  jobs.n[3] = 65536;
  jobs.s[4] = Wo_h;  jobs.d[4] = Wo_h_b;  jobs.n[4] = 147456;
  jobs.s[5] = Wo_w;  jobs.d[5] = Wo_w_b;  jobs.n[5] = 147456;
  jobs.s[6] = Wmlpc; jobs.d[6] = Wmlpc_b; jobs.n[6] = 147456;
  jobs.s[7] = Wp;    jobs.d[7] = Wp_b;    jobs.n[7] = 147456;
  k0_cvt<<<dim3(144, 8), 256, 0, stream>>>(jobs);

  k1_mixer<<<4096, 256, 0, stream>>>(x, Wc_h_b, bc_h, Wg_h_b, bg_h,
      Wc_w_b, bc_w, Wg_w_b, bg_w, y_h, y_w, wmode, psum_yh, psum_yw, psum_x);

  k3_scales<<<64, 384, 0, stream>>>(psum_yh, psum_yw, psum_x, Wo_h, bo_h,
      Wo_w, bo_w, Wmlpc, Wr1, br1, Wr2, br2, scal);

  if (wmode) {
    k24_final_A<<<1024, 512, 0, stream>>>(x, y_h, y_w,
        Wo_h_b, Wo_w_b, Wmlpc_b, Wp_b, bo_h, bo_w, bp, scal, out);
  } else {
    k24_final_B<<<512, 512, 0, stream>>>(x, y_h, Wc_w_b, bc_w, Wg_w_b, bg_w,
        Wo_h_b, Wo_w_b, Wmlpc_b, Wp_b, bo_h, bo_w, bp, scal, out);
  }
}

// Round 7
// 779.451 us; speedup vs baseline: 1.0406x; 1.0406x over previous
//
#include <hip/hip_runtime.h>

typedef unsigned short u16;
typedef __bf16 bf16_t;
typedef bf16_t bf16x8 __attribute__((ext_vector_type(8)));
typedef float f32x4 __attribute__((ext_vector_type(4)));

__device__ __forceinline__ u16 f2b(float f) {
  union { float f; unsigned u; } v; v.f = f;
  unsigned r = (v.u + 0x7fffu + ((v.u >> 16) & 1u)) >> 16;
  return (u16)r;
}
__device__ __forceinline__ float b2f(u16 b) {
  union { unsigned u; float f; } v; v.u = ((unsigned)b) << 16;
  return v.f;
}
__device__ __forceinline__ f32x4 mfma16(bf16x8 a, bf16x8 b, f32x4 c) {
  return __builtin_amdgcn_mfma_f32_16x16x32_bf16(a, b, c, 0, 0, 0);
}

// ---------------- K0: fp32 -> bf16 weight conversion ----------------
struct CvtJobs {
  const float* s[8];
  u16* d[8];
  int n[8];
};
__global__ void k0_cvt(CvtJobs j) {
  int job = blockIdx.y;
  const float* s = j.s[job];
  u16* d = j.d[job];
  int n = j.n[job];
  int stride = gridDim.x * blockDim.x * 4;
  for (int i = (blockIdx.x * blockDim.x + threadIdx.x) * 4; i < n; i += stride) {
    float4 v = *(const float4*)(s + i);
    ushort4 o4;
    o4.x = f2b(v.x); o4.y = f2b(v.y); o4.z = f2b(v.z); o4.w = f2b(v.w);
    *(ushort4*)(d + i) = o4;
  }
}

#define LW 392   // xs_b row pitch (u16)
#define TW 40    // xs_t row pitch (k1 only)
#define AW 40    // attn row pitch

// ---------------- K1: h-path full mix (+psum_yh, psum_x), w-path pool-only (psum_yw) ----------------
// Exact R2 known-good version.
__global__ __launch_bounds__(256, 2) void k1_mixer(
    const float* __restrict__ x,
    const u16* __restrict__ Wc_h_b, const float* __restrict__ bc_h,
    const u16* __restrict__ Wg_h_b, const float* __restrict__ bg_h,
    const u16* __restrict__ Wc_w_b, const float* __restrict__ bc_w,
    const u16* __restrict__ Wg_w_b, const float* __restrict__ bg_w,
    u16* __restrict__ y_h,
    float* __restrict__ psum_yh, float* __restrict__ psum_yw,
    float* __restrict__ psum_x)
{
  __shared__ u16 xs_b[32 * LW];     // x rows [l][c] bf16; later y tile [j][c] (path 0)
  __shared__ u16 xs_t[384 * TW];    // transposed [c][l] (path 0 only)
  __shared__ u16 attn[8 * 32 * AW]; // [h][j][l]
  __shared__ u16 whead[16 * 72];    // [h pad16][k=64]
  __shared__ float rs[8 * 32];      // [h][l] attn row-sums (path 1 only)

  const int tid = threadIdx.x;
  const int bid = blockIdx.x;
  const int path = bid >> 11;
  const int n = bid & 2047;
  const int b = n >> 5, o = n & 31;
  long base; int strideL;
  if (path == 0) { base = (long)b * 393216 + (long)o * 384;   strideL = 12288; }
  else           { base = (long)b * 393216 + (long)o * 12288; strideL = 384; }
  const float* xseq = x + base;

  const u16* Wc_b = path ? Wc_w_b : Wc_h_b;
  const float* bc = path ? bc_w : bc_h;
  const u16* Wg_b = path ? Wg_w_b : Wg_h_b;
  const float* bg = path ? bg_w : bg_h;

  // ---- load x-seq -> xs_b bf16 ----
  for (int i = tid; i < 3072; i += 256) {
    int l = i / 96, c4 = (i % 96) * 4;
    float4 v = *(const float4*)(xseq + (long)l * strideL + c4);
    ushort4 w4;
    w4.x = f2b(v.x); w4.y = f2b(v.y); w4.z = f2b(v.z); w4.w = f2b(v.w);
    *(ushort4*)&xs_b[l * LW + c4] = w4;
  }
  for (int i = tid; i < 576; i += 256) whead[576 + i] = 0;
  __syncthreads();

  if (path == 0) {
    // transpose for the mix A-operand
    for (int i = tid; i < 3072; i += 256) {
      int c = i % 384, l4 = (i / 384) * 4;
      ushort4 w4;
      w4.x = xs_b[(l4 + 0) * LW + c];
      w4.y = xs_b[(l4 + 1) * LW + c];
      w4.z = xs_b[(l4 + 2) * LW + c];
      w4.w = xs_b[(l4 + 3) * LW + c];
      *(ushort4*)&xs_t[c * TW + l4] = w4;
    }
    // per-seq x column sums (deterministic psum slot)
    for (int c = tid; c < 384; c += 256) {
      float s = 0.f;
      for (int l = 0; l < 32; l++) s += b2f(xs_b[l * LW + c]);
      psum_x[(long)n * 384 + c] = s;
    }
  }

  const int wave = tid >> 6, lane = tid & 63;
  const int lq = lane >> 4, lr = lane & 15;
  const f32x4 z = {0.f, 0.f, 0.f, 0.f};

  // ---- compress ----
  if (wave < 2) {
    f32x4 acc = z;
    for (int ks = 0; ks < 12; ks++) {
      bf16x8 af  = *(const bf16x8*)&xs_b[(wave * 16 + lr) * LW + ks * 32 + lq * 8];
      bf16x8 bfr = *(const bf16x8*)(Wc_b + lr * 384 + ks * 32 + lq * 8);
      acc = mfma16(af, bfr, acc);
    }
    float bcv = bc[lr];
    for (int r = 0; r < 4; r++) {
      int l = wave * 16 + lq * 4 + r;
      whead[(lr >> 1) * 72 + l * 2 + (lr & 1)] = f2b(acc[r] + bcv);
    }
  }
  __syncthreads();

  // ---- generate ----
  {
    bf16x8 ga0 = *(const bf16x8*)&whead[lr * 72 + lq * 8];
    bf16x8 ga1 = *(const bf16x8*)&whead[lr * 72 + 32 + lq * 8];
    for (int t = 0; t < 16; t++) {
      int nt = wave * 16 + t;
      const u16* wg = Wg_b + (nt * 16 + lr) * 64;
      bf16x8 gb0 = *(const bf16x8*)(wg + lq * 8);
      bf16x8 gb1 = *(const bf16x8*)(wg + 32 + lq * 8);
      f32x4 acc = z;
      acc = mfma16(ga0, gb0, acc);
      acc = mfma16(ga1, gb1, acc);
      if (lq < 2) {
        int m = nt * 16 + lr, ii = m >> 5, jj = m & 31;
        for (int r = 0; r < 4; r++)
          attn[((lq * 4 + r) * 32 + jj) * AW + ii] = f2b(acc[r]);
      }
    }
  }
  __syncthreads();

  // ---- softmax over l per (h, j) ----
  {
    int h = tid >> 5, j = tid & 31;
    u16* row = &attn[(h * 32 + j) * AW];
    float v[32]; float mx = -1e30f;
    for (int i = 0; i < 32; i++) {
      v[i] = b2f(row[i]) + bg[i * 32 + j];
      mx = fmaxf(mx, v[i]);
    }
    float s = 0.f;
    for (int i = 0; i < 32; i++) { v[i] = __expf(v[i] - mx); s += v[i]; }
    float inv = 1.0f / s;
    for (int i = 0; i < 32; i++) row[i] = f2b(v[i] * inv);
  }
  __syncthreads();

  if (path == 0) {
    // ---- mix: y[j][c] ----
    for (int hh = 0; hh < 2; hh++) {
      int h = wave * 2 + hh;
      bf16x8 bf0 = *(const bf16x8*)&attn[(h * 32 + lr) * AW + lq * 8];
      bf16x8 bf1 = *(const bf16x8*)&attn[(h * 32 + 16 + lr) * AW + lq * 8];
      for (int mt = 0; mt < 3; mt++) {
        bf16x8 af = *(const bf16x8*)&xs_t[(h * 48 + mt * 16 + lr) * TW + lq * 8];
        f32x4 a0 = mfma16(af, bf0, z);
        f32x4 a1 = mfma16(af, bf1, z);
        for (int r = 0; r < 4; r++) {
          int c = h * 48 + mt * 16 + lq * 4 + r;
          xs_b[lr * LW + c]        = f2b(a0[r]);
          xs_b[(16 + lr) * LW + c] = f2b(a1[r]);
        }
      }
    }
    __syncthreads();
    // store y_h + per-seq column sums
    u16* yout = y_h + base;
    for (int i = tid; i < 1536; i += 256) {
      int l = i / 48, uu = (i % 48) * 8;
      *(uint4*)(yout + (long)l * strideL + uu) = *(const uint4*)&xs_b[l * LW + uu];
    }
    for (int c = tid; c < 384; c += 256) {
      float s = 0.f;
      for (int jj = 0; jj < 32; jj++) s += b2f(xs_b[jj * LW + c]);
      psum_yh[(long)n * 384 + c] = s;
    }
  } else {
    // ---- pool-only: sum_j y[j][c] = sum_l xs[l][c] * rs[h(c)][l] ----
    {
      int h = tid >> 5, l = tid & 31;
      float s = 0.f;
      for (int j = 0; j < 32; j++) s += b2f(attn[(h * 32 + j) * AW + l]);
      rs[h * 32 + l] = s;
    }
    __syncthreads();
    for (int c = tid; c < 384; c += 256) {
      int h = c / 48;
      float s = 0.f;
      for (int l = 0; l < 32; l++) s += b2f(xs_b[l * LW + c]) * rs[h * 32 + l];
      psum_yw[(long)n * 384 + c] = s;
    }
  }
}

// ---------------- K3: psums -> reweighting scales ----------------
__global__ __launch_bounds__(384) void k3_scales(
    const float* __restrict__ psum_yh, const float* __restrict__ psum_yw,
    const float* __restrict__ psum_x,
    const float* __restrict__ Wo_h, const float* __restrict__ bo_h,
    const float* __restrict__ Wo_w, const float* __restrict__ bo_w,
    const float* __restrict__ Wmlpc,
    const float* __restrict__ Wr1, const float* __restrict__ br1,
    const float* __restrict__ Wr2, const float* __restrict__ br2,
    float* __restrict__ scal)
{
  __shared__ float ph[384], pw[384], px[384], a[384], r1[96];
  int b = blockIdx.x, t = threadIdx.x;
  float sh = 0.f, sw = 0.f, sx = 0.f;
  for (int o = 0; o < 32; o++) {
    sh += psum_yh[(long)(b * 32 + o) * 384 + t];
    sw += psum_yw[(long)(b * 32 + o) * 384 + t];
    sx += psum_x[(long)(b * 32 + o) * 384 + t];
  }
  ph[t] = sh; pw[t] = sw; px[t] = sx;
  __syncthreads();
  float s1 = 0.f, s2 = 0.f, s3 = 0.f;
  for (int k = 0; k < 384; k++) {
    s1 += ph[k] * Wo_h[t * 384 + k];
    s2 += pw[k] * Wo_w[t * 384 + k];
    s3 += px[k] * Wmlpc[t * 384 + k];
  }
  a[t] = (s1 + s2 + s3) * (1.f / 1024.f) + bo_h[t] + bo_w[t];
  __syncthreads();
  if (t < 96) {
    float s = 0.f;
    for (int k = 0; k < 384; k++) s += a[k] * Wr1[t * 384 + k];
    s += br1[t];
    r1[t] = s * 0.5f * (1.f + erff(s * 0.70710678118654752f));
  }
  __syncthreads();
  {
    float sv[3];
    for (int si = 0; si < 3; si++) {
      float acc = 0.f;
      for (int k = 0; k < 96; k++) acc += r1[k] * Wr2[(t * 3 + si) * 96 + k];
      sv[si] = acc + br2[t * 3 + si];
    }
    float mx = fmaxf(sv[0], fmaxf(sv[1], sv[2]));
    float e0 = __expf(sv[0] - mx), e1 = __expf(sv[1] - mx), e2 = __expf(sv[2] - mx);
    float inv = 1.f / (e0 + e1 + e2);
    scal[0 * 24576 + b * 384 + t] = e0 * inv;   // h
    scal[1 * 24576 + b * 384 + t] = e1 * inv;   // w
    scal[2 * 24576 + b * 384 + t] = e2 * inv;   // c
  }
}

// ---- barrier-free GEMM, 64-row tile: acc += bufA @ Bglob^T ----
// B from global (L2-resident weights), depth-1 register prefetch; A via
// ds_read_b128 from bufA. No __syncthreads inside.
__device__ __forceinline__ void gemm64(
    const u16* __restrict__ Bglob, const u16* __restrict__ bufA,
    f32x4 acc[2][6], int wm, int wn, int lq, int lr)
{
  const u16* bp0 = Bglob + (wn * 96 + lr) * 384 + lq * 8;
  const u16* ap0 = bufA + (wm * 32 + lr) * 392 + lq * 8;
  bf16x8 bcur[6], af[2];
#pragma unroll
  for (int nt = 0; nt < 6; nt++) bcur[nt] = *(const bf16x8*)(bp0 + nt * 6144);
#pragma unroll
  for (int mt = 0; mt < 2; mt++) af[mt] = *(const bf16x8*)(ap0 + mt * 6272);
  for (int ks = 0; ks < 12; ks++) {
    bf16x8 bnx[6], an[2];
    const int k1 = (ks < 11 ? ks + 1 : 11) * 32;  // last iter: dead reload
#pragma unroll
    for (int nt = 0; nt < 6; nt++) bnx[nt] = *(const bf16x8*)(bp0 + nt * 6144 + k1);
#pragma unroll
    for (int mt = 0; mt < 2; mt++) an[mt] = *(const bf16x8*)(ap0 + mt * 6272 + k1);
#pragma unroll
    for (int nt = 0; nt < 6; nt++)
#pragma unroll
      for (int mt = 0; mt < 2; mt++)
        acc[mt][nt] = mfma16(af[mt], bcur[nt], acc[mt][nt]);
#pragma unroll
    for (int nt = 0; nt < 6; nt++) bcur[nt] = bnx[nt];
#pragma unroll
    for (int mt = 0; mt < 2; mt++) af[mt] = an[mt];
  }
}

// ---------------- K24: 64-token tile, w-recompute dataflow, 2 blocks/CU ----------------
// grid 1024. LDS = 72,960 B (bufA 50K + attn 20K + whead 2.3K) -> 2 blocks/CU.
// The mix's A-operand (x^T) reads directly from global x (L2-hot) — no Bs, no transpose.
// acc = T_c; *= s2/s1; (recompute y_w in bufA); += T_w; *= s1/s0; += T_h;
// comb = acc*s0 + s0*bo_h + s1*bo_w; out = comb @ Wp^T + bp.
__global__ __launch_bounds__(512, 4) void k24_final(
    const float* __restrict__ x, const u16* __restrict__ y_h,
    const u16* __restrict__ Wc_w_b, const float* __restrict__ bc_w,
    const u16* __restrict__ Wg_w_b, const float* __restrict__ bg_w,
    const u16* __restrict__ Wo_h_b, const u16* __restrict__ Wo_w_b,
    const u16* __restrict__ Wmlpc_b, const u16* __restrict__ Wp_b,
    const float* __restrict__ bo_h, const float* __restrict__ bo_w,
    const float* __restrict__ bp,
    const float* __restrict__ scal, float* __restrict__ out)
{
  __shared__ u16 bufA[64 * 392];    // x -> y_w -> y_h -> comb (50,176 B)
  __shared__ u16 attn[8 * 32 * AW]; // 20,480 B
  __shared__ u16 whead[16 * 72];    //  2,304 B

  const int tid = threadIdx.x;
  const int m0 = blockIdx.x * 64;
  const int b = m0 >> 10;
  const int wave = tid >> 6, lane = tid & 63;
  const int lq = lane >> 4, lr = lane & 15;
  const int wm = wave >> 2, wn = wave & 3;
  const f32x4 z = {0.f, 0.f, 0.f, 0.f};

  // stage x fp32 -> bufA bf16
  for (int i = tid; i < 6144; i += 512) {
    int row = i / 96, c4 = (i % 96) * 4;
    float4 v = *(const float4*)(x + (long)(m0 + row) * 384 + c4);
    ushort4 w4;
    w4.x = f2b(v.x); w4.y = f2b(v.y); w4.z = f2b(v.z); w4.w = f2b(v.w);
    *(ushort4*)&bufA[row * 392 + c4] = w4;
  }
  for (int i = tid; i < 576; i += 512) whead[576 + i] = 0;
  __syncthreads();

  f32x4 acc[2][6];
#pragma unroll
  for (int i = 0; i < 2; i++)
#pragma unroll
    for (int jn = 0; jn < 6; jn++) acc[i][jn] = z;

  // src = c: acc = T_c
  gemm64(Wmlpc_b, bufA, acc, wm, wn, lq, lr);
  {
    const float* s2p = scal + 2 * 24576 + b * 384;
    const float* s1p = scal + 1 * 24576 + b * 384;
#pragma unroll
    for (int nt = 0; nt < 6; nt++) {
      int col = wn * 96 + nt * 16 + lr;
      float r = s2p[col] / fmaxf(s1p[col], 1e-30f);
#pragma unroll
      for (int mt = 0; mt < 2; mt++)
#pragma unroll
        for (int rr = 0; rr < 4; rr++) acc[mt][nt][rr] *= r;
    }
  }

  // ---- w-path recompute: 2 sequences (32 tokens each) overwrite their bufA rows with y_w ----
  for (int q = 0; q < 2; q++) {
    // compress (2 waves)
    if (wave < 2) {
      f32x4 ac = z;
      for (int ks = 0; ks < 12; ks++) {
        bf16x8 afg = *(const bf16x8*)&bufA[(q * 32 + wave * 16 + lr) * 392 + ks * 32 + lq * 8];
        bf16x8 bfg = *(const bf16x8*)(Wc_w_b + lr * 384 + ks * 32 + lq * 8);
        ac = mfma16(afg, bfg, ac);
      }
      float bcv = bc_w[lr];
      for (int r = 0; r < 4; r++) {
        int l = wave * 16 + lq * 4 + r;
        whead[(lr >> 1) * 72 + l * 2 + (lr & 1)] = f2b(ac[r] + bcv);
      }
    }
    __syncthreads();
    // generate (8 waves x 8 n-tiles)
    {
      bf16x8 ga0 = *(const bf16x8*)&whead[lr * 72 + lq * 8];
      bf16x8 ga1 = *(const bf16x8*)&whead[lr * 72 + 32 + lq * 8];
      for (int t = 0; t < 8; t++) {
        int nt = wave * 8 + t;
        const u16* wg = Wg_w_b + (nt * 16 + lr) * 64;
        bf16x8 gb0 = *(const bf16x8*)(wg + lq * 8);
        bf16x8 gb1 = *(const bf16x8*)(wg + 32 + lq * 8);
        f32x4 ac = z;
        ac = mfma16(ga0, gb0, ac);
        ac = mfma16(ga1, gb1, ac);
        if (lq < 2) {
          int m = nt * 16 + lr, ii = m >> 5, jj = m & 31;
          for (int r = 0; r < 4; r++)
            attn[((lq * 4 + r) * 32 + jj) * AW + ii] = f2b(ac[r]);
        }
      }
    }
    __syncthreads();
    // softmax
    if (tid < 256) {
      int h = tid >> 5, j = tid & 31;
      u16* row = &attn[(h * 32 + j) * AW];
      float v[32]; float mx = -1e30f;
      for (int i = 0; i < 32; i++) {
        v[i] = b2f(row[i]) + bg_w[i * 32 + j];
        mx = fmaxf(mx, v[i]);
      }
      float s = 0.f;
      for (int i = 0; i < 32; i++) { v[i] = __expf(v[i] - mx); s += v[i]; }
      float inv = 1.0f / s;
      for (int i = 0; i < 32; i++) row[i] = f2b(v[i] * inv);
    }
    __syncthreads();
    // mix: wave = head; A-fragment (x^T) direct from global (bit-identical to old
    // LDS-transpose path: same f2b rounding). Overwrites bufA rows q*32..q*32+31.
    {
      int h = wave;
      bf16x8 bf0 = *(const bf16x8*)&attn[(h * 32 + lr) * AW + lq * 8];
      bf16x8 bf1 = *(const bf16x8*)&attn[(h * 32 + 16 + lr) * AW + lq * 8];
      const float* xg = x + (long)(m0 + q * 32 + lq * 8) * 384;
      for (int mt = 0; mt < 3; mt++) {
        int ca = h * 48 + mt * 16 + lr;
        alignas(16) u16 tmp[8];
#pragma unroll
        for (int e = 0; e < 8; e++) tmp[e] = f2b(xg[(long)e * 384 + ca]);
        bf16x8 afg = *(const bf16x8*)tmp;
        f32x4 a0 = mfma16(afg, bf0, z);
        f32x4 a1 = mfma16(afg, bf1, z);
        for (int r = 0; r < 4; r++) {
          int c = h * 48 + mt * 16 + lq * 4 + r;
          bufA[(q * 32 + lr) * 392 + c]      = f2b(a0[r]);
          bufA[(q * 32 + 16 + lr) * 392 + c] = f2b(a1[r]);
        }
      }
    }
    __syncthreads();
  }

  // src = w: acc += T_w (bufA holds y_w)
  gemm64(Wo_w_b, bufA, acc, wm, wn, lq, lr);
  {
    const float* s1p = scal + 1 * 24576 + b * 384;
    const float* s0p = scal + 0 * 24576 + b * 384;
#pragma unroll
    for (int nt = 0; nt < 6; nt++) {
      int col = wn * 96 + nt * 16 + lr;
      float r = s1p[col] / fmaxf(s0p[col], 1e-30f);
#pragma unroll
      for (int mt = 0; mt < 2; mt++)
#pragma unroll
        for (int rr = 0; rr < 4; rr++) acc[mt][nt][rr] *= r;
    }
  }
  __syncthreads();   // all bufA reads done before overwrite with y_h

  // stage y_h
  for (int i = tid; i < 3072; i += 512) {
    int row = i / 48, u8 = (i % 48) * 8;
    *(uint4*)&bufA[row * 392 + u8] = *(const uint4*)(y_h + (long)(m0 + row) * 384 + u8);
  }
  __syncthreads();

  // src = h: acc += T_h
  gemm64(Wo_h_b, bufA, acc, wm, wn, lq, lr);
  __syncthreads();   // all bufA reads done before comb dump

  // comb = acc*s0 + s0*bo_h + s1*bo_w -> bufA bf16
  {
    const float* s0p = scal + 0 * 24576 + b * 384;
    const float* s1p = scal + 1 * 24576 + b * 384;
#pragma unroll
    for (int nt = 0; nt < 6; nt++) {
      int col = wn * 96 + nt * 16 + lr;
      float s0v = s0p[col];
      float bcb = s0v * bo_h[col] + s1p[col] * bo_w[col];
#pragma unroll
      for (int mt = 0; mt < 2; mt++)
#pragma unroll
        for (int r = 0; r < 4; r++) {
          int row = wm * 32 + mt * 16 + lq * 4 + r;
          bufA[row * 392 + col] = f2b(acc[mt][nt][r] * s0v + bcb);
        }
    }
  }
  __syncthreads();

  // out = comb @ Wp^T + bp
#pragma unroll
  for (int i = 0; i < 2; i++)
#pragma unroll
    for (int jn = 0; jn < 6; jn++) acc[i][jn] = z;
  gemm64(Wp_b, bufA, acc, wm, wn, lq, lr);
#pragma unroll
  for (int nt = 0; nt < 6; nt++) {
    int col = wn * 96 + nt * 16 + lr;
    float bi = bp[col];
#pragma unroll
    for (int mt = 0; mt < 2; mt++)
#pragma unroll
      for (int r = 0; r < 4; r++) {
        int row = m0 + wm * 32 + mt * 16 + lq * 4 + r;
        out[(long)row * 384 + col] = acc[mt][nt][r] + bi;
      }
  }
}

// ---------------- host ----------------
extern "C" void kernel_launch(void* const* d_in, const int* in_sizes, int n_in,
                              void* d_out, int out_size, void* d_ws, size_t ws_size,
                              hipStream_t stream) {
  const float* x     = (const float*)d_in[0];
  const float* Wc_h  = (const float*)d_in[1];
  const float* bc_h  = (const float*)d_in[2];
  const float* Wg_h  = (const float*)d_in[3];
  const float* bg_h  = (const float*)d_in[4];
  const float* Wo_h  = (const float*)d_in[5];
  const float* bo_h  = (const float*)d_in[6];
  const float* Wc_w  = (const float*)d_in[7];
  const float* bc_w  = (const float*)d_in[8];
  const float* Wg_w  = (const float*)d_in[9];
  const float* bg_w  = (const float*)d_in[10];
  const float* Wo_w  = (const float*)d_in[11];
  const float* bo_w  = (const float*)d_in[12];
  const float* Wmlpc = (const float*)d_in[13];
  const float* Wr1   = (const float*)d_in[14];
  const float* br1   = (const float*)d_in[15];
  const float* Wr2   = (const float*)d_in[16];
  const float* br2   = (const float*)d_in[17];
  const float* Wp    = (const float*)d_in[18];
  const float* bp    = (const float*)d_in[19];
  float* out = (float*)d_out;

  // workspace layout: 61,530,112 bytes total (~58.7 MB)
  char* ws = (char*)d_ws;
  u16* y_h       = (u16*)(ws + 0);          // 50,331,648
  float* psum_yh = (float*)(ws + 50331648); //  3,145,728
  float* psum_yw = (float*)(ws + 53477376); //  3,145,728
  float* psum_x  = (float*)(ws + 56623104); //  3,145,728
  float* scal    = (float*)(ws + 59768832); //    294,912
  u16* Wc_h_b    = (u16*)(ws + 60063744);
  u16* Wc_w_b    = (u16*)(ws + 60076032);
  u16* Wg_h_b    = (u16*)(ws + 60088320);
  u16* Wg_w_b    = (u16*)(ws + 60219392);
  u16* Wo_h_b    = (u16*)(ws + 60350464);
  u16* Wo_w_b    = (u16*)(ws + 60645376);
  u16* Wmlpc_b   = (u16*)(ws + 60940288);
  u16* Wp_b      = (u16*)(ws + 61235200);

  CvtJobs jobs;
  jobs.s[0] = Wc_h;  jobs.d[0] = Wc_h_b;  jobs.n[0] = 6144;
  jobs.s[1] = Wc_w;  jobs.d[1] = Wc_w_b;  jobs.n[1] = 6144;
  jobs.s[2] = Wg_h;  jobs.d[2] = Wg_h_b;  jobs.n[2] = 65536;
  jobs.s[3] = Wg_w;  jobs.d[3] = Wg_w_b;  jobs.n[3] = 65536;
  jobs.s[4] = Wo_h;  jobs.d[4] = Wo_h_b;  jobs.n[4] = 147456;
  jobs.s[5] = Wo_w;  jobs.d[5] = Wo_w_b;  jobs.n[5] = 147456;
  jobs.s[6] = Wmlpc; jobs.d[6] = Wmlpc_b; jobs.n[6] = 147456;
  jobs.s[7] = Wp;    jobs.d[7] = Wp_b;    jobs.n[7] = 147456;
  k0_cvt<<<dim3(144, 8), 256, 0, stream>>>(jobs);

  k1_mixer<<<4096, 256, 0, stream>>>(x, Wc_h_b, bc_h, Wg_h_b, bg_h,
      Wc_w_b, bc_w, Wg_w_b, bg_w, y_h, psum_yh, psum_yw, psum_x);

  k3_scales<<<64, 384, 0, stream>>>(psum_yh, psum_yw, psum_x, Wo_h, bo_h,
      Wo_w, bo_w, Wmlpc, Wr1, br1, Wr2, br2, scal);

  k24_final<<<1024, 512, 0, stream>>>(x, y_h, Wc_w_b, bc_w, Wg_w_b, bg_w,
      Wo_h_b, Wo_w_b, Wmlpc_b, Wp_b, bo_h, bo_w, bp, scal, out);
}

// Round 8
// 756.261 us; speedup vs baseline: 1.0725x; 1.0307x over previous
//
#include <hip/hip_runtime.h>

typedef unsigned short u16;
typedef __bf16 bf16_t;
typedef bf16_t bf16x8 __attribute__((ext_vector_type(8)));
typedef float f32x4 __attribute__((ext_vector_type(4)));

__device__ __forceinline__ u16 f2b(float f) {
  union { float f; unsigned u; } v; v.f = f;
  unsigned r = (v.u + 0x7fffu + ((v.u >> 16) & 1u)) >> 16;
  return (u16)r;
}
__device__ __forceinline__ float b2f(u16 b) {
  union { unsigned u; float f; } v; v.u = ((unsigned)b) << 16;
  return v.f;
}
__device__ __forceinline__ f32x4 mfma16(bf16x8 a, bf16x8 b, f32x4 c) {
  return __builtin_amdgcn_mfma_f32_16x16x32_bf16(a, b, c, 0, 0, 0);
}

// ---------------- K0: fp32 -> bf16 weight conversion ----------------
struct CvtJobs {
  const float* s[8];
  u16* d[8];
  int n[8];
};
__global__ void k0_cvt(CvtJobs j) {
  int job = blockIdx.y;
  const float* s = j.s[job];
  u16* d = j.d[job];
  int n = j.n[job];
  int stride = gridDim.x * blockDim.x * 4;
  for (int i = (blockIdx.x * blockDim.x + threadIdx.x) * 4; i < n; i += stride) {
    float4 v = *(const float4*)(s + i);
    ushort4 o4;
    o4.x = f2b(v.x); o4.y = f2b(v.y); o4.z = f2b(v.z); o4.w = f2b(v.w);
    *(ushort4*)(d + i) = o4;
  }
}

#define LW 392   // xs_b row pitch (u16)
#define TW 40    // xs_t row pitch (k1 only)
#define AW 40    // attn row pitch

// ---------------- K1: h-path full mix (+psum_yh, psum_x), w-path pool-only (psum_yw) ----------------
// Exact R2 known-good version.
__global__ __launch_bounds__(256, 2) void k1_mixer(
    const float* __restrict__ x,
    const u16* __restrict__ Wc_h_b, const float* __restrict__ bc_h,
    const u16* __restrict__ Wg_h_b, const float* __restrict__ bg_h,
    const u16* __restrict__ Wc_w_b, const float* __restrict__ bc_w,
    const u16* __restrict__ Wg_w_b, const float* __restrict__ bg_w,
    u16* __restrict__ y_h,
    float* __restrict__ psum_yh, float* __restrict__ psum_yw,
    float* __restrict__ psum_x)
{
  __shared__ u16 xs_b[32 * LW];     // x rows [l][c] bf16; later y tile [j][c] (path 0)
  __shared__ u16 xs_t[384 * TW];    // transposed [c][l] (path 0 only)
  __shared__ u16 attn[8 * 32 * AW]; // [h][j][l]
  __shared__ u16 whead[16 * 72];    // [h pad16][k=64]
  __shared__ float rs[8 * 32];      // [h][l] attn row-sums (path 1 only)

  const int tid = threadIdx.x;
  const int bid = blockIdx.x;
  const int path = bid >> 11;
  const int n = bid & 2047;
  const int b = n >> 5, o = n & 31;
  long base; int strideL;
  if (path == 0) { base = (long)b * 393216 + (long)o * 384;   strideL = 12288; }
  else           { base = (long)b * 393216 + (long)o * 12288; strideL = 384; }
  const float* xseq = x + base;

  const u16* Wc_b = path ? Wc_w_b : Wc_h_b;
  const float* bc = path ? bc_w : bc_h;
  const u16* Wg_b = path ? Wg_w_b : Wg_h_b;
  const float* bg = path ? bg_w : bg_h;

  // ---- load x-seq -> xs_b bf16 ----
  for (int i = tid; i < 3072; i += 256) {
    int l = i / 96, c4 = (i % 96) * 4;
    float4 v = *(const float4*)(xseq + (long)l * strideL + c4);
    ushort4 w4;
    w4.x = f2b(v.x); w4.y = f2b(v.y); w4.z = f2b(v.z); w4.w = f2b(v.w);
    *(ushort4*)&xs_b[l * LW + c4] = w4;
  }
  for (int i = tid; i < 576; i += 256) whead[576 + i] = 0;
  __syncthreads();

  if (path == 0) {
    // transpose for the mix A-operand
    for (int i = tid; i < 3072; i += 256) {
      int c = i % 384, l4 = (i / 384) * 4;
      ushort4 w4;
      w4.x = xs_b[(l4 + 0) * LW + c];
      w4.y = xs_b[(l4 + 1) * LW + c];
      w4.z = xs_b[(l4 + 2) * LW + c];
      w4.w = xs_b[(l4 + 3) * LW + c];
      *(ushort4*)&xs_t[c * TW + l4] = w4;
    }
    // per-seq x column sums (deterministic psum slot)
    for (int c = tid; c < 384; c += 256) {
      float s = 0.f;
      for (int l = 0; l < 32; l++) s += b2f(xs_b[l * LW + c]);
      psum_x[(long)n * 384 + c] = s;
    }
  }

  const int wave = tid >> 6, lane = tid & 63;
  const int lq = lane >> 4, lr = lane & 15;
  const f32x4 z = {0.f, 0.f, 0.f, 0.f};

  // ---- compress ----
  if (wave < 2) {
    f32x4 acc = z;
    for (int ks = 0; ks < 12; ks++) {
      bf16x8 af  = *(const bf16x8*)&xs_b[(wave * 16 + lr) * LW + ks * 32 + lq * 8];
      bf16x8 bfr = *(const bf16x8*)(Wc_b + lr * 384 + ks * 32 + lq * 8);
      acc = mfma16(af, bfr, acc);
    }
    float bcv = bc[lr];
    for (int r = 0; r < 4; r++) {
      int l = wave * 16 + lq * 4 + r;
      whead[(lr >> 1) * 72 + l * 2 + (lr & 1)] = f2b(acc[r] + bcv);
    }
  }
  __syncthreads();

  // ---- generate ----
  {
    bf16x8 ga0 = *(const bf16x8*)&whead[lr * 72 + lq * 8];
    bf16x8 ga1 = *(const bf16x8*)&whead[lr * 72 + 32 + lq * 8];
    for (int t = 0; t < 16; t++) {
      int nt = wave * 16 + t;
      const u16* wg = Wg_b + (nt * 16 + lr) * 64;
      bf16x8 gb0 = *(const bf16x8*)(wg + lq * 8);
      bf16x8 gb1 = *(const bf16x8*)(wg + 32 + lq * 8);
      f32x4 acc = z;
      acc = mfma16(ga0, gb0, acc);
      acc = mfma16(ga1, gb1, acc);
      if (lq < 2) {
        int m = nt * 16 + lr, ii = m >> 5, jj = m & 31;
        for (int r = 0; r < 4; r++)
          attn[((lq * 4 + r) * 32 + jj) * AW + ii] = f2b(acc[r]);
      }
    }
  }
  __syncthreads();

  // ---- softmax over l per (h, j) ----
  {
    int h = tid >> 5, j = tid & 31;
    u16* row = &attn[(h * 32 + j) * AW];
    float v[32]; float mx = -1e30f;
    for (int i = 0; i < 32; i++) {
      v[i] = b2f(row[i]) + bg[i * 32 + j];
      mx = fmaxf(mx, v[i]);
    }
    float s = 0.f;
    for (int i = 0; i < 32; i++) { v[i] = __expf(v[i] - mx); s += v[i]; }
    float inv = 1.0f / s;
    for (int i = 0; i < 32; i++) row[i] = f2b(v[i] * inv);
  }
  __syncthreads();

  if (path == 0) {
    // ---- mix: y[j][c] ----
    for (int hh = 0; hh < 2; hh++) {
      int h = wave * 2 + hh;
      bf16x8 bf0 = *(const bf16x8*)&attn[(h * 32 + lr) * AW + lq * 8];
      bf16x8 bf1 = *(const bf16x8*)&attn[(h * 32 + 16 + lr) * AW + lq * 8];
      for (int mt = 0; mt < 3; mt++) {
        bf16x8 af = *(const bf16x8*)&xs_t[(h * 48 + mt * 16 + lr) * TW + lq * 8];
        f32x4 a0 = mfma16(af, bf0, z);
        f32x4 a1 = mfma16(af, bf1, z);
        for (int r = 0; r < 4; r++) {
          int c = h * 48 + mt * 16 + lq * 4 + r;
          xs_b[lr * LW + c]        = f2b(a0[r]);
          xs_b[(16 + lr) * LW + c] = f2b(a1[r]);
        }
      }
    }
    __syncthreads();
    // store y_h + per-seq column sums
    u16* yout = y_h + base;
    for (int i = tid; i < 1536; i += 256) {
      int l = i / 48, uu = (i % 48) * 8;
      *(uint4*)(yout + (long)l * strideL + uu) = *(const uint4*)&xs_b[l * LW + uu];
    }
    for (int c = tid; c < 384; c += 256) {
      float s = 0.f;
      for (int jj = 0; jj < 32; jj++) s += b2f(xs_b[jj * LW + c]);
      psum_yh[(long)n * 384 + c] = s;
    }
  } else {
    // ---- pool-only: sum_j y[j][c] = sum_l xs[l][c] * rs[h(c)][l] ----
    {
      int h = tid >> 5, l = tid & 31;
      float s = 0.f;
      for (int j = 0; j < 32; j++) s += b2f(attn[(h * 32 + j) * AW + l]);
      rs[h * 32 + l] = s;
    }
    __syncthreads();
    for (int c = tid; c < 384; c += 256) {
      int h = c / 48;
      float s = 0.f;
      for (int l = 0; l < 32; l++) s += b2f(xs_b[l * LW + c]) * rs[h * 32 + l];
      psum_yw[(long)n * 384 + c] = s;
    }
  }
}

// ---------------- K3: psums -> reweighting scales ----------------
__global__ __launch_bounds__(384) void k3_scales(
    const float* __restrict__ psum_yh, const float* __restrict__ psum_yw,
    const float* __restrict__ psum_x,
    const float* __restrict__ Wo_h, const float* __restrict__ bo_h,
    const float* __restrict__ Wo_w, const float* __restrict__ bo_w,
    const float* __restrict__ Wmlpc,
    const float* __restrict__ Wr1, const float* __restrict__ br1,
    const float* __restrict__ Wr2, const float* __restrict__ br2,
    float* __restrict__ scal)
{
  __shared__ float ph[384], pw[384], px[384], a[384], r1[96];
  int b = blockIdx.x, t = threadIdx.x;
  float sh = 0.f, sw = 0.f, sx = 0.f;
  for (int o = 0; o < 32; o++) {
    sh += psum_yh[(long)(b * 32 + o) * 384 + t];
    sw += psum_yw[(long)(b * 32 + o) * 384 + t];
    sx += psum_x[(long)(b * 32 + o) * 384 + t];
  }
  ph[t] = sh; pw[t] = sw; px[t] = sx;
  __syncthreads();
  float s1 = 0.f, s2 = 0.f, s3 = 0.f;
  for (int k = 0; k < 384; k++) {
    s1 += ph[k] * Wo_h[t * 384 + k];
    s2 += pw[k] * Wo_w[t * 384 + k];
    s3 += px[k] * Wmlpc[t * 384 + k];
  }
  a[t] = (s1 + s2 + s3) * (1.f / 1024.f) + bo_h[t] + bo_w[t];
  __syncthreads();
  if (t < 96) {
    float s = 0.f;
    for (int k = 0; k < 384; k++) s += a[k] * Wr1[t * 384 + k];
    s += br1[t];
    r1[t] = s * 0.5f * (1.f + erff(s * 0.70710678118654752f));
  }
  __syncthreads();
  {
    float sv[3];
    for (int si = 0; si < 3; si++) {
      float acc = 0.f;
      for (int k = 0; k < 96; k++) acc += r1[k] * Wr2[(t * 3 + si) * 96 + k];
      sv[si] = acc + br2[t * 3 + si];
    }
    float mx = fmaxf(sv[0], fmaxf(sv[1], sv[2]));
    float e0 = __expf(sv[0] - mx), e1 = __expf(sv[1] - mx), e2 = __expf(sv[2] - mx);
    float inv = 1.f / (e0 + e1 + e2);
    scal[0 * 24576 + b * 384 + t] = e0 * inv;   // h
    scal[1 * 24576 + b * 384 + t] = e1 * inv;   // w
    scal[2 * 24576 + b * 384 + t] = e2 * inv;   // c
  }
}

// ---- barrier-free GEMM, 64-row tile: acc += bufA @ Bglob^T ----
__device__ __forceinline__ void gemm64(
    const u16* __restrict__ Bglob, const u16* __restrict__ bufA,
    f32x4 acc[2][6], int wm, int wn, int lq, int lr)
{
  const u16* bp0 = Bglob + (wn * 96 + lr) * 384 + lq * 8;
  const u16* ap0 = bufA + (wm * 32 + lr) * 392 + lq * 8;
  bf16x8 bcur[6], af[2];
#pragma unroll
  for (int nt = 0; nt < 6; nt++) bcur[nt] = *(const bf16x8*)(bp0 + nt * 6144);
#pragma unroll
  for (int mt = 0; mt < 2; mt++) af[mt] = *(const bf16x8*)(ap0 + mt * 6272);
  for (int ks = 0; ks < 12; ks++) {
    bf16x8 bnx[6], an[2];
    const int k1 = (ks < 11 ? ks + 1 : 11) * 32;  // last iter: dead reload
#pragma unroll
    for (int nt = 0; nt < 6; nt++) bnx[nt] = *(const bf16x8*)(bp0 + nt * 6144 + k1);
#pragma unroll
    for (int mt = 0; mt < 2; mt++) an[mt] = *(const bf16x8*)(ap0 + mt * 6272 + k1);
#pragma unroll
    for (int nt = 0; nt < 6; nt++)
#pragma unroll
      for (int mt = 0; mt < 2; mt++)
        acc[mt][nt] = mfma16(af[mt], bcur[nt], acc[mt][nt]);
#pragma unroll
    for (int nt = 0; nt < 6; nt++) bcur[nt] = bnx[nt];
#pragma unroll
    for (int mt = 0; mt < 2; mt++) af[mt] = an[mt];
  }
}

// ---------------- K24: 64-token tile, w-recompute dataflow, 2 blocks/CU ----------------
// vs R7: (1) mix A-fragments read from bufA (LDS) with read/barrier/write split —
// no global x re-read; (2) out written via fp32 LDS bounce in 32-row chunks —
// every 128B line stored once, fully coalesced; (3) bijective XCD swizzle.
__global__ __launch_bounds__(512, 4) void k24_final(
    const float* __restrict__ x, const u16* __restrict__ y_h,
    const u16* __restrict__ Wc_w_b, const float* __restrict__ bc_w,
    const u16* __restrict__ Wg_w_b, const float* __restrict__ bg_w,
    const u16* __restrict__ Wo_h_b, const u16* __restrict__ Wo_w_b,
    const u16* __restrict__ Wmlpc_b, const u16* __restrict__ Wp_b,
    const float* __restrict__ bo_h, const float* __restrict__ bo_w,
    const float* __restrict__ bp,
    const float* __restrict__ scal, float* __restrict__ out)
{
  __shared__ __align__(16) char smem[64 * 392 * 2];  // bufA (u16 64x392) / fbuf (f32 32x388)
  __shared__ u16 attn[8 * 32 * AW];                  // 20,480 B
  __shared__ u16 whead[16 * 72];                     //  2,304 B
  u16* bufA = (u16*)smem;
  float* fbuf = (float*)smem;

  const int tid = threadIdx.x;
  // bijective XCD swizzle (1024 % 8 == 0): each XCD gets a contiguous 128-block chunk
  const int bid = (blockIdx.x & 7) * 128 + (blockIdx.x >> 3);
  const int m0 = bid * 64;
  const int b = m0 >> 10;
  const int wave = tid >> 6, lane = tid & 63;
  const int lq = lane >> 4, lr = lane & 15;
  const int wm = wave >> 2, wn = wave & 3;
  const f32x4 z = {0.f, 0.f, 0.f, 0.f};

  // stage x fp32 -> bufA bf16
  for (int i = tid; i < 6144; i += 512) {
    int row = i / 96, c4 = (i % 96) * 4;
    float4 v = *(const float4*)(x + (long)(m0 + row) * 384 + c4);
    ushort4 w4;
    w4.x = f2b(v.x); w4.y = f2b(v.y); w4.z = f2b(v.z); w4.w = f2b(v.w);
    *(ushort4*)&bufA[row * 392 + c4] = w4;
  }
  for (int i = tid; i < 576; i += 512) whead[576 + i] = 0;
  __syncthreads();

  f32x4 acc[2][6];
#pragma unroll
  for (int i = 0; i < 2; i++)
#pragma unroll
    for (int jn = 0; jn < 6; jn++) acc[i][jn] = z;

  // src = c: acc = T_c
  gemm64(Wmlpc_b, bufA, acc, wm, wn, lq, lr);
  {
    const float* s2p = scal + 2 * 24576 + b * 384;
    const float* s1p = scal + 1 * 24576 + b * 384;
#pragma unroll
    for (int nt = 0; nt < 6; nt++) {
      int col = wn * 96 + nt * 16 + lr;
      float r = s2p[col] / fmaxf(s1p[col], 1e-30f);
#pragma unroll
      for (int mt = 0; mt < 2; mt++)
#pragma unroll
        for (int rr = 0; rr < 4; rr++) acc[mt][nt][rr] *= r;
    }
  }

  // ---- w-path recompute: 2 sequences (32 tokens each) overwrite their bufA rows with y_w ----
  for (int q = 0; q < 2; q++) {
    // compress (2 waves)
    if (wave < 2) {
      f32x4 ac = z;
      for (int ks = 0; ks < 12; ks++) {
        bf16x8 afg = *(const bf16x8*)&bufA[(q * 32 + wave * 16 + lr) * 392 + ks * 32 + lq * 8];
        bf16x8 bfg = *(const bf16x8*)(Wc_w_b + lr * 384 + ks * 32 + lq * 8);
        ac = mfma16(afg, bfg, ac);
      }
      float bcv = bc_w[lr];
      for (int r = 0; r < 4; r++) {
        int l = wave * 16 + lq * 4 + r;
        whead[(lr >> 1) * 72 + l * 2 + (lr & 1)] = f2b(ac[r] + bcv);
      }
    }
    __syncthreads();
    // generate (8 waves x 8 n-tiles)
    {
      bf16x8 ga0 = *(const bf16x8*)&whead[lr * 72 + lq * 8];
      bf16x8 ga1 = *(const bf16x8*)&whead[lr * 72 + 32 + lq * 8];
      for (int t = 0; t < 8; t++) {
        int nt = wave * 8 + t;
        const u16* wg = Wg_w_b + (nt * 16 + lr) * 64;
        bf16x8 gb0 = *(const bf16x8*)(wg + lq * 8);
        bf16x8 gb1 = *(const bf16x8*)(wg + 32 + lq * 8);
        f32x4 ac = z;
        ac = mfma16(ga0, gb0, ac);
        ac = mfma16(ga1, gb1, ac);
        if (lq < 2) {
          int m = nt * 16 + lr, ii = m >> 5, jj = m & 31;
          for (int r = 0; r < 4; r++)
            attn[((lq * 4 + r) * 32 + jj) * AW + ii] = f2b(ac[r]);
        }
      }
    }
    __syncthreads();
    // softmax
    if (tid < 256) {
      int h = tid >> 5, j = tid & 31;
      u16* row = &attn[(h * 32 + j) * AW];
      float v[32]; float mx = -1e30f;
      for (int i = 0; i < 32; i++) {
        v[i] = b2f(row[i]) + bg_w[i * 32 + j];
        mx = fmaxf(mx, v[i]);
      }
      float s = 0.f;
      for (int i = 0; i < 32; i++) { v[i] = __expf(v[i] - mx); s += v[i]; }
      float inv = 1.0f / s;
      for (int i = 0; i < 32; i++) row[i] = f2b(v[i] * inv);
    }
    __syncthreads();
    // mix: wave = head. READ phase (x^T fragments from bufA via scalar LDS reads)
    // -> barrier -> WRITE phase (overwrite bufA rows q*32.. with y_w).
    {
      int h = wave;
      bf16x8 bf0 = *(const bf16x8*)&attn[(h * 32 + lr) * AW + lq * 8];
      bf16x8 bf1 = *(const bf16x8*)&attn[(h * 32 + 16 + lr) * AW + lq * 8];
      bf16x8 afr[3];
#pragma unroll
      for (int mt = 0; mt < 3; mt++) {
        int ca = h * 48 + mt * 16 + lr;
        alignas(16) u16 tmp[8];
#pragma unroll
        for (int e = 0; e < 8; e++) tmp[e] = bufA[(q * 32 + lq * 8 + e) * 392 + ca];
        afr[mt] = *(const bf16x8*)tmp;
      }
      __syncthreads();   // all x reads complete before overwrite
#pragma unroll
      for (int mt = 0; mt < 3; mt++) {
        f32x4 a0 = mfma16(afr[mt], bf0, z);
        f32x4 a1 = mfma16(afr[mt], bf1, z);
        for (int r = 0; r < 4; r++) {
          int c = h * 48 + mt * 16 + lq * 4 + r;
          bufA[(q * 32 + lr) * 392 + c]      = f2b(a0[r]);
          bufA[(q * 32 + 16 + lr) * 392 + c] = f2b(a1[r]);
        }
      }
    }
    __syncthreads();
  }

  // src = w: acc += T_w (bufA holds y_w)
  gemm64(Wo_w_b, bufA, acc, wm, wn, lq, lr);
  {
    const float* s1p = scal + 1 * 24576 + b * 384;
    const float* s0p = scal + 0 * 24576 + b * 384;
#pragma unroll
    for (int nt = 0; nt < 6; nt++) {
      int col = wn * 96 + nt * 16 + lr;
      float r = s1p[col] / fmaxf(s0p[col], 1e-30f);
#pragma unroll
      for (int mt = 0; mt < 2; mt++)
#pragma unroll
        for (int rr = 0; rr < 4; rr++) acc[mt][nt][rr] *= r;
    }
  }
  __syncthreads();   // all bufA reads done before overwrite with y_h

  // stage y_h
  for (int i = tid; i < 3072; i += 512) {
    int row = i / 48, u8 = (i % 48) * 8;
    *(uint4*)&bufA[row * 392 + u8] = *(const uint4*)(y_h + (long)(m0 + row) * 384 + u8);
  }
  __syncthreads();

  // src = h: acc += T_h
  gemm64(Wo_h_b, bufA, acc, wm, wn, lq, lr);
  __syncthreads();   // all bufA reads done before comb dump

  // comb = acc*s0 + s0*bo_h + s1*bo_w -> bufA bf16
  {
    const float* s0p = scal + 0 * 24576 + b * 384;
    const float* s1p = scal + 1 * 24576 + b * 384;
#pragma unroll
    for (int nt = 0; nt < 6; nt++) {
      int col = wn * 96 + nt * 16 + lr;
      float s0v = s0p[col];
      float bcb = s0v * bo_h[col] + s1p[col] * bo_w[col];
#pragma unroll
      for (int mt = 0; mt < 2; mt++)
#pragma unroll
        for (int r = 0; r < 4; r++) {
          int row = wm * 32 + mt * 16 + lq * 4 + r;
          bufA[row * 392 + col] = f2b(acc[mt][nt][r] * s0v + bcb);
        }
    }
  }
  __syncthreads();

  // out = comb @ Wp^T + bp
#pragma unroll
  for (int i = 0; i < 2; i++)
#pragma unroll
    for (int jn = 0; jn < 6; jn++) acc[i][jn] = z;
  gemm64(Wp_b, bufA, acc, wm, wn, lq, lr);
  __syncthreads();   // comb reads complete; bufA reusable as fbuf

  // ---- epilogue: fp32 LDS bounce, 2 chunks of 32 rows; full-line coalesced stores ----
  for (int chunk = 0; chunk < 2; chunk++) {
    if (wm == chunk) {
#pragma unroll
      for (int nt = 0; nt < 6; nt++) {
        int col = wn * 96 + nt * 16 + lr;
        float bi = bp[col];
#pragma unroll
        for (int mt = 0; mt < 2; mt++)
#pragma unroll
          for (int r = 0; r < 4; r++) {
            int rowl = mt * 16 + lq * 4 + r;
            fbuf[rowl * 388 + col] = acc[mt][nt][r] + bi;  // pitch 388: bank-rotate
          }
      }
    }
    __syncthreads();
    for (int i = tid; i < 3072; i += 512) {
      int rowl = i / 96, c4 = (i % 96) * 4;
      *(float4*)(out + (long)(m0 + chunk * 32 + rowl) * 384 + c4) =
          *(const float4*)&fbuf[rowl * 388 + c4];
    }
    __syncthreads();
  }
}

// ---------------- host ----------------
extern "C" void kernel_launch(void* const* d_in, const int* in_sizes, int n_in,
                              void* d_out, int out_size, void* d_ws, size_t ws_size,
                              hipStream_t stream) {
  const float* x     = (const float*)d_in[0];
  const float* Wc_h  = (const float*)d_in[1];
  const float* bc_h  = (const float*)d_in[2];
  const float* Wg_h  = (const float*)d_in[3];
  const float* bg_h  = (const float*)d_in[4];
  const float* Wo_h  = (const float*)d_in[5];
  const float* bo_h  = (const float*)d_in[6];
  const float* Wc_w  = (const float*)d_in[7];
  const float* bc_w  = (const float*)d_in[8];
  const float* Wg_w  = (const float*)d_in[9];
  const float* bg_w  = (const float*)d_in[10];
  const float* Wo_w  = (const float*)d_in[11];
  const float* bo_w  = (const float*)d_in[12];
  const float* Wmlpc = (const float*)d_in[13];
  const float* Wr1   = (const float*)d_in[14];
  const float* br1   = (const float*)d_in[15];
  const float* Wr2   = (const float*)d_in[16];
  const float* br2   = (const float*)d_in[17];
  const float* Wp    = (const float*)d_in[18];
  const float* bp    = (const float*)d_in[19];
  float* out = (float*)d_out;

  // workspace layout: 61,530,112 bytes total (~58.7 MB)
  char* ws = (char*)d_ws;
  u16* y_h       = (u16*)(ws + 0);          // 50,331,648
  float* psum_yh = (float*)(ws + 50331648); //  3,145,728
  float* psum_yw = (float*)(ws + 53477376); //  3,145,728
  float* psum_x  = (float*)(ws + 56623104); //  3,145,728
  float* scal    = (float*)(ws + 59768832); //    294,912
  u16* Wc_h_b    = (u16*)(ws + 60063744);
  u16* Wc_w_b    = (u16*)(ws + 60076032);
  u16* Wg_h_b    = (u16*)(ws + 60088320);
  u16* Wg_w_b    = (u16*)(ws + 60219392);
  u16* Wo_h_b    = (u16*)(ws + 60350464);
  u16* Wo_w_b    = (u16*)(ws + 60645376);
  u16* Wmlpc_b   = (u16*)(ws + 60940288);
  u16* Wp_b      = (u16*)(ws + 61235200);

  CvtJobs jobs;
  jobs.s[0] = Wc_h;  jobs.d[0] = Wc_h_b;  jobs.n[0] = 6144;
  jobs.s[1] = Wc_w;  jobs.d[1] = Wc_w_b;  jobs.n[1] = 6144;
  jobs.s[2] = Wg_h;  jobs.d[2] = Wg_h_b;  jobs.n[2] = 65536;
  jobs.s[3] = Wg_w;  jobs.d[3] = Wg_w_b;  jobs.n[3] = 65536;
  jobs.s[4] = Wo_h;  jobs.d[4] = Wo_h_b;  jobs.n[4] = 147456;
  jobs.s[5] = Wo_w;  jobs.d[5] = Wo_w_b;  jobs.n[5] = 147456;
  jobs.s[6] = Wmlpc; jobs.d[6] = Wmlpc_b; jobs.n[6] = 147456;
  jobs.s[7] = Wp;    jobs.d[7] = Wp_b;    jobs.n[7] = 147456;
  k0_cvt<<<dim3(144, 8), 256, 0, stream>>>(jobs);

  k1_mixer<<<4096, 256, 0, stream>>>(x, Wc_h_b, bc_h, Wg_h_b, bg_h,
      Wc_w_b, bc_w, Wg_w_b, bg_w, y_h, psum_yh, psum_yw, psum_x);

  k3_scales<<<64, 384, 0, stream>>>(psum_yh, psum_yw, psum_x, Wo_h, bo_h,
      Wo_w, bo_w, Wmlpc, Wr1, br1, Wr2, br2, scal);

  k24_final<<<1024, 512, 0, stream>>>(x, y_h, Wc_w_b, bc_w, Wg_w_b, bg_w,
      Wo_h_b, Wo_w_b, Wmlpc_b, Wp_b, bo_h, bo_w, bp, scal, out);
}

// Round 9
// 630.732 us; speedup vs baseline: 1.2859x; 1.1990x over previous
//
#include <hip/hip_runtime.h>

typedef unsigned short u16;
typedef __bf16 bf16_t;
typedef bf16_t bf16x8 __attribute__((ext_vector_type(8)));
typedef float f32x4 __attribute__((ext_vector_type(4)));

__device__ __forceinline__ u16 f2b(float f) {
  union { float f; unsigned u; } v; v.f = f;
  unsigned r = (v.u + 0x7fffu + ((v.u >> 16) & 1u)) >> 16;
  return (u16)r;
}
__device__ __forceinline__ float b2f(u16 b) {
  union { unsigned u; float f; } v; v.u = ((unsigned)b) << 16;
  return v.f;
}
__device__ __forceinline__ f32x4 mfma16(bf16x8 a, bf16x8 b, f32x4 c) {
  return __builtin_amdgcn_mfma_f32_16x16x32_bf16(a, b, c, 0, 0, 0);
}

// ---------------- K0: fp32 -> bf16 weight conversion ----------------
struct CvtJobs {
  const float* s[8];
  u16* d[8];
  int n[8];
};
__global__ void k0_cvt(CvtJobs j) {
  int job = blockIdx.y;
  const float* s = j.s[job];
  u16* d = j.d[job];
  int n = j.n[job];
  int stride = gridDim.x * blockDim.x * 4;
  for (int i = (blockIdx.x * blockDim.x + threadIdx.x) * 4; i < n; i += stride) {
    float4 v = *(const float4*)(s + i);
    ushort4 o4;
    o4.x = f2b(v.x); o4.y = f2b(v.y); o4.z = f2b(v.z); o4.w = f2b(v.w);
    *(ushort4*)(d + i) = o4;
  }
}

#define LW 392   // xs_b row pitch (u16)
#define TW 40    // Bs row pitch (k24)
#define AW 40    // attn row pitch

// ---------------- K1: h-path full mix (+psum_yh, psum_x), w-path pool-only (psum_yw) ----------------
// vs R2: xs_t transpose buffer DELETED (mix A-fragments scalar-read from xs_b with
// read/barrier/write split — bit-identical values). LDS 80 -> 48.9 KB => 3 blocks/CU.
// Bijective XCD swizzle (4096 % 8 == 0).
__global__ __launch_bounds__(256, 3) void k1_mixer(
    const float* __restrict__ x,
    const u16* __restrict__ Wc_h_b, const float* __restrict__ bc_h,
    const u16* __restrict__ Wg_h_b, const float* __restrict__ bg_h,
    const u16* __restrict__ Wc_w_b, const float* __restrict__ bc_w,
    const u16* __restrict__ Wg_w_b, const float* __restrict__ bg_w,
    u16* __restrict__ y_h,
    float* __restrict__ psum_yh, float* __restrict__ psum_yw,
    float* __restrict__ psum_x)
{
  __shared__ u16 xs_b[32 * LW];     // 25,088 B: x rows [l][c]; later y tile [j][c] (path 0)
  __shared__ u16 attn[8 * 32 * AW]; // 20,480 B: [h][j][l]
  __shared__ u16 whead[16 * 72];    //  2,304 B: [h pad16][k=64]
  __shared__ float rs[8 * 32];      //  1,024 B: [h][l] attn row-sums (path 1 only)

  const int tid = threadIdx.x;
  // bijective XCD swizzle: each XCD gets a contiguous 512-block chunk
  const int bid = (blockIdx.x & 7) * 512 + (blockIdx.x >> 3);
  const int path = bid >> 11;
  const int n = bid & 2047;
  const int b = n >> 5, o = n & 31;
  long base; int strideL;
  if (path == 0) { base = (long)b * 393216 + (long)o * 384;   strideL = 12288; }
  else           { base = (long)b * 393216 + (long)o * 12288; strideL = 384; }
  const float* xseq = x + base;

  const u16* Wc_b = path ? Wc_w_b : Wc_h_b;
  const float* bc = path ? bc_w : bc_h;
  const u16* Wg_b = path ? Wg_w_b : Wg_h_b;
  const float* bg = path ? bg_w : bg_h;

  // ---- load x-seq -> xs_b bf16 ----
  for (int i = tid; i < 3072; i += 256) {
    int l = i / 96, c4 = (i % 96) * 4;
    float4 v = *(const float4*)(xseq + (long)l * strideL + c4);
    ushort4 w4;
    w4.x = f2b(v.x); w4.y = f2b(v.y); w4.z = f2b(v.z); w4.w = f2b(v.w);
    *(ushort4*)&xs_b[l * LW + c4] = w4;
  }
  for (int i = tid; i < 576; i += 256) whead[576 + i] = 0;
  __syncthreads();

  if (path == 0) {
    // per-seq x column sums (deterministic psum slot)
    for (int c = tid; c < 384; c += 256) {
      float s = 0.f;
      for (int l = 0; l < 32; l++) s += b2f(xs_b[l * LW + c]);
      psum_x[(long)n * 384 + c] = s;
    }
  }

  const int wave = tid >> 6, lane = tid & 63;
  const int lq = lane >> 4, lr = lane & 15;
  const f32x4 z = {0.f, 0.f, 0.f, 0.f};

  // ---- compress ----
  if (wave < 2) {
    f32x4 acc = z;
    for (int ks = 0; ks < 12; ks++) {
      bf16x8 af  = *(const bf16x8*)&xs_b[(wave * 16 + lr) * LW + ks * 32 + lq * 8];
      bf16x8 bfr = *(const bf16x8*)(Wc_b + lr * 384 + ks * 32 + lq * 8);
      acc = mfma16(af, bfr, acc);
    }
    float bcv = bc[lr];
    for (int r = 0; r < 4; r++) {
      int l = wave * 16 + lq * 4 + r;
      whead[(lr >> 1) * 72 + l * 2 + (lr & 1)] = f2b(acc[r] + bcv);
    }
  }
  __syncthreads();

  // ---- generate ----
  {
    bf16x8 ga0 = *(const bf16x8*)&whead[lr * 72 + lq * 8];
    bf16x8 ga1 = *(const bf16x8*)&whead[lr * 72 + 32 + lq * 8];
    for (int t = 0; t < 16; t++) {
      int nt = wave * 16 + t;
      const u16* wg = Wg_b + (nt * 16 + lr) * 64;
      bf16x8 gb0 = *(const bf16x8*)(wg + lq * 8);
      bf16x8 gb1 = *(const bf16x8*)(wg + 32 + lq * 8);
      f32x4 acc = z;
      acc = mfma16(ga0, gb0, acc);
      acc = mfma16(ga1, gb1, acc);
      if (lq < 2) {
        int m = nt * 16 + lr, ii = m >> 5, jj = m & 31;
        for (int r = 0; r < 4; r++)
          attn[((lq * 4 + r) * 32 + jj) * AW + ii] = f2b(acc[r]);
      }
    }
  }
  __syncthreads();

  // ---- softmax over l per (h, j) ----
  {
    int h = tid >> 5, j = tid & 31;
    u16* row = &attn[(h * 32 + j) * AW];
    float v[32]; float mx = -1e30f;
    for (int i = 0; i < 32; i++) {
      v[i] = b2f(row[i]) + bg[i * 32 + j];
      mx = fmaxf(mx, v[i]);
    }
    float s = 0.f;
    for (int i = 0; i < 32; i++) { v[i] = __expf(v[i] - mx); s += v[i]; }
    float inv = 1.0f / s;
    for (int i = 0; i < 32; i++) row[i] = f2b(v[i] * inv);
  }
  __syncthreads();

  if (path == 0) {
    // ---- mix: y[j][c]. READ x^T fragments from xs_b (both heads, all mt) ->
    // barrier -> compute + overwrite xs_b with y. Same f2b-rounded values as the
    // old xs_t path: bit-identical numerics. ----
    const int h0 = wave * 2;
    bf16x8 afr[6];
#pragma unroll
    for (int hh = 0; hh < 2; hh++)
#pragma unroll
      for (int mt = 0; mt < 3; mt++) {
        int c = (h0 + hh) * 48 + mt * 16 + lr;
        alignas(16) u16 tmp[8];
#pragma unroll
        for (int e = 0; e < 8; e++) tmp[e] = xs_b[(lq * 8 + e) * LW + c];
        afr[hh * 3 + mt] = *(const bf16x8*)tmp;
      }
    __syncthreads();   // all x reads complete before y overwrite
    for (int hh = 0; hh < 2; hh++) {
      int h = h0 + hh;
      bf16x8 bf0 = *(const bf16x8*)&attn[(h * 32 + lr) * AW + lq * 8];
      bf16x8 bf1 = *(const bf16x8*)&attn[(h * 32 + 16 + lr) * AW + lq * 8];
      for (int mt = 0; mt < 3; mt++) {
        f32x4 a0 = mfma16(afr[hh * 3 + mt], bf0, z);
        f32x4 a1 = mfma16(afr[hh * 3 + mt], bf1, z);
        for (int r = 0; r < 4; r++) {
          int c = h * 48 + mt * 16 + lq * 4 + r;
          xs_b[lr * LW + c]        = f2b(a0[r]);
          xs_b[(16 + lr) * LW + c] = f2b(a1[r]);
        }
      }
    }
    __syncthreads();
    // store y_h + per-seq column sums
    u16* yout = y_h + base;
    for (int i = tid; i < 1536; i += 256) {
      int l = i / 48, uu = (i % 48) * 8;
      *(uint4*)(yout + (long)l * strideL + uu) = *(const uint4*)&xs_b[l * LW + uu];
    }
    for (int c = tid; c < 384; c += 256) {
      float s = 0.f;
      for (int jj = 0; jj < 32; jj++) s += b2f(xs_b[jj * LW + c]);
      psum_yh[(long)n * 384 + c] = s;
    }
  } else {
    // ---- pool-only: sum_j y[j][c] = sum_l xs[l][c] * rs[h(c)][l] ----
    {
      int h = tid >> 5, l = tid & 31;
      float s = 0.f;
      for (int j = 0; j < 32; j++) s += b2f(attn[(h * 32 + j) * AW + l]);
      rs[h * 32 + l] = s;
    }
    __syncthreads();
    for (int c = tid; c < 384; c += 256) {
      int h = c / 48;
      float s = 0.f;
      for (int l = 0; l < 32; l++) s += b2f(xs_b[l * LW + c]) * rs[h * 32 + l];
      psum_yw[(long)n * 384 + c] = s;
    }
  }
}

// ---------------- K3: psums -> reweighting scales ----------------
__global__ __launch_bounds__(384) void k3_scales(
    const float* __restrict__ psum_yh, const float* __restrict__ psum_yw,
    const float* __restrict__ psum_x,
    const float* __restrict__ Wo_h, const float* __restrict__ bo_h,
    const float* __restrict__ Wo_w, const float* __restrict__ bo_w,
    const float* __restrict__ Wmlpc,
    const float* __restrict__ Wr1, const float* __restrict__ br1,
    const float* __restrict__ Wr2, const float* __restrict__ br2,
    float* __restrict__ scal)
{
  __shared__ float ph[384], pw[384], px[384], a[384], r1[96];
  int b = blockIdx.x, t = threadIdx.x;
  float sh = 0.f, sw = 0.f, sx = 0.f;
  for (int o = 0; o < 32; o++) {
    sh += psum_yh[(long)(b * 32 + o) * 384 + t];
    sw += psum_yw[(long)(b * 32 + o) * 384 + t];
    sx += psum_x[(long)(b * 32 + o) * 384 + t];
  }
  ph[t] = sh; pw[t] = sw; px[t] = sx;
  __syncthreads();
  float s1 = 0.f, s2 = 0.f, s3 = 0.f;
  for (int k = 0; k < 384; k++) {
    s1 += ph[k] * Wo_h[t * 384 + k];
    s2 += pw[k] * Wo_w[t * 384 + k];
    s3 += px[k] * Wmlpc[t * 384 + k];
  }
  a[t] = (s1 + s2 + s3) * (1.f / 1024.f) + bo_h[t] + bo_w[t];
  __syncthreads();
  if (t < 96) {
    float s = 0.f;
    for (int k = 0; k < 384; k++) s += a[k] * Wr1[t * 384 + k];
    s += br1[t];
    r1[t] = s * 0.5f * (1.f + erff(s * 0.70710678118654752f));
  }
  __syncthreads();
  {
    float sv[3];
    for (int si = 0; si < 3; si++) {
      float acc = 0.f;
      for (int k = 0; k < 96; k++) acc += r1[k] * Wr2[(t * 3 + si) * 96 + k];
      sv[si] = acc + br2[t * 3 + si];
    }
    float mx = fmaxf(sv[0], fmaxf(sv[1], sv[2]));
    float e0 = __expf(sv[0] - mx), e1 = __expf(sv[1] - mx), e2 = __expf(sv[2] - mx);
    float inv = 1.f / (e0 + e1 + e2);
    scal[0 * 24576 + b * 384 + t] = e0 * inv;   // h
    scal[1 * 24576 + b * 384 + t] = e1 * inv;   // w
    scal[2 * 24576 + b * 384 + t] = e2 * inv;   // c
  }
}

// ---- barrier-free GEMM, 128-row tile: acc += bufA @ Bglob^T (exact R2) ----
__device__ __forceinline__ void gemm128(
    const u16* __restrict__ Bglob, const u16* __restrict__ bufA,
    f32x4 acc[4][6], int wm, int wn, int lq, int lr)
{
  const u16* bp0 = Bglob + (wn * 96 + lr) * 384 + lq * 8;
  const u16* ap0 = bufA + (wm * 64 + lr) * 392 + lq * 8;
  bf16x8 bcur[6], af[4];
#pragma unroll
  for (int nt = 0; nt < 6; nt++) bcur[nt] = *(const bf16x8*)(bp0 + nt * 6144);
#pragma unroll
  for (int mt = 0; mt < 4; mt++) af[mt] = *(const bf16x8*)(ap0 + mt * 6272);
  for (int ks = 0; ks < 12; ks++) {
    bf16x8 bnx[6], an[4];
    const int k1 = (ks < 11 ? ks + 1 : 11) * 32;
#pragma unroll
    for (int nt = 0; nt < 6; nt++) bnx[nt] = *(const bf16x8*)(bp0 + nt * 6144 + k1);
#pragma unroll
    for (int mt = 0; mt < 4; mt++) an[mt] = *(const bf16x8*)(ap0 + mt * 6272 + k1);
#pragma unroll
    for (int nt = 0; nt < 6; nt++)
#pragma unroll
      for (int mt = 0; mt < 4; mt++)
        acc[mt][nt] = mfma16(af[mt], bcur[nt], acc[mt][nt]);
#pragma unroll
    for (int nt = 0; nt < 6; nt++) bcur[nt] = bnx[nt];
#pragma unroll
    for (int mt = 0; mt < 4; mt++) af[mt] = an[mt];
  }
}

// ---------------- K24: exact R2 known-good (253 us) ----------------
__global__ __launch_bounds__(512, 2) void k24_final(
    const float* __restrict__ x, const u16* __restrict__ y_h,
    const u16* __restrict__ Wc_w_b, const float* __restrict__ bc_w,
    const u16* __restrict__ Wg_w_b, const float* __restrict__ bg_w,
    const u16* __restrict__ Wo_h_b, const u16* __restrict__ Wo_w_b,
    const u16* __restrict__ Wmlpc_b, const u16* __restrict__ Wp_b,
    const float* __restrict__ bo_h, const float* __restrict__ bo_w,
    const float* __restrict__ bp,
    const float* __restrict__ scal, float* __restrict__ out)
{
  __shared__ u16 bufA[128 * 392];
  __shared__ u16 Bs[384 * 40];
  __shared__ u16 attn[8 * 32 * AW];
  __shared__ u16 whead[16 * 72];

  const int tid = threadIdx.x;
  const int m0 = blockIdx.x * 128;
  const int b = m0 >> 10;
  const int wave = tid >> 6, lane = tid & 63;
  const int lq = lane >> 4, lr = lane & 15;
  const int wm = wave >> 2, wn = wave & 3;
  const f32x4 z = {0.f, 0.f, 0.f, 0.f};

  for (int i = tid; i < 12288; i += 512) {
    int row = i / 96, c4 = (i % 96) * 4;
    float4 v = *(const float4*)(x + (long)(m0 + row) * 384 + c4);
    ushort4 w4;
    w4.x = f2b(v.x); w4.y = f2b(v.y); w4.z = f2b(v.z); w4.w = f2b(v.w);
    *(ushort4*)&bufA[row * 392 + c4] = w4;
  }
  for (int i = tid; i < 576; i += 512) whead[576 + i] = 0;
  __syncthreads();

  f32x4 acc[4][6];
#pragma unroll
  for (int i = 0; i < 4; i++)
#pragma unroll
    for (int jn = 0; jn < 6; jn++) acc[i][jn] = z;

  gemm128(Wmlpc_b, bufA, acc, wm, wn, lq, lr);
  {
    const float* s2p = scal + 2 * 24576 + b * 384;
    const float* s1p = scal + 1 * 24576 + b * 384;
#pragma unroll
    for (int nt = 0; nt < 6; nt++) {
      int col = wn * 96 + nt * 16 + lr;
      float r = s2p[col] / fmaxf(s1p[col], 1e-30f);
#pragma unroll
      for (int mt = 0; mt < 4; mt++)
#pragma unroll
        for (int rr = 0; rr < 4; rr++) acc[mt][nt][rr] *= r;
    }
  }

  for (int q = 0; q < 4; q++) {
    for (int i = tid; i < 3072; i += 512) {
      int c = i % 384, l4 = (i / 384) * 4;
      ushort4 w4;
      w4.x = bufA[(q * 32 + l4 + 0) * 392 + c];
      w4.y = bufA[(q * 32 + l4 + 1) * 392 + c];
      w4.z = bufA[(q * 32 + l4 + 2) * 392 + c];
      w4.w = bufA[(q * 32 + l4 + 3) * 392 + c];
      *(ushort4*)&Bs[c * 40 + l4] = w4;
    }
    if (wave < 2) {
      f32x4 ac = z;
      for (int ks = 0; ks < 12; ks++) {
        bf16x8 afg = *(const bf16x8*)&bufA[(q * 32 + wave * 16 + lr) * 392 + ks * 32 + lq * 8];
        bf16x8 bfg = *(const bf16x8*)(Wc_w_b + lr * 384 + ks * 32 + lq * 8);
        ac = mfma16(afg, bfg, ac);
      }
      float bcv = bc_w[lr];
      for (int r = 0; r < 4; r++) {
        int l = wave * 16 + lq * 4 + r;
        whead[(lr >> 1) * 72 + l * 2 + (lr & 1)] = f2b(ac[r] + bcv);
      }
    }
    __syncthreads();
    {
      bf16x8 ga0 = *(const bf16x8*)&whead[lr * 72 + lq * 8];
      bf16x8 ga1 = *(const bf16x8*)&whead[lr * 72 + 32 + lq * 8];
      for (int t = 0; t < 8; t++) {
        int nt = wave * 8 + t;
        const u16* wg = Wg_w_b + (nt * 16 + lr) * 64;
        bf16x8 gb0 = *(const bf16x8*)(wg + lq * 8);
        bf16x8 gb1 = *(const bf16x8*)(wg + 32 + lq * 8);
        f32x4 ac = z;
        ac = mfma16(ga0, gb0, ac);
        ac = mfma16(ga1, gb1, ac);
        if (lq < 2) {
          int m = nt * 16 + lr, ii = m >> 5, jj = m & 31;
          for (int r = 0; r < 4; r++)
            attn[((lq * 4 + r) * 32 + jj) * AW + ii] = f2b(ac[r]);
        }
      }
    }
    __syncthreads();
    if (tid < 256) {
      int h = tid >> 5, j = tid & 31;
      u16* row = &attn[(h * 32 + j) * AW];
      float v[32]; float mx = -1e30f;
      for (int i = 0; i < 32; i++) {
        v[i] = b2f(row[i]) + bg_w[i * 32 + j];
        mx = fmaxf(mx, v[i]);
      }
      float s = 0.f;
      for (int i = 0; i < 32; i++) { v[i] = __expf(v[i] - mx); s += v[i]; }
      float inv = 1.0f / s;
      for (int i = 0; i < 32; i++) row[i] = f2b(v[i] * inv);
    }
    __syncthreads();
    {
      int h = wave;
      bf16x8 bf0 = *(const bf16x8*)&attn[(h * 32 + lr) * AW + lq * 8];
      bf16x8 bf1 = *(const bf16x8*)&attn[(h * 32 + 16 + lr) * AW + lq * 8];
      for (int mt = 0; mt < 3; mt++) {
        bf16x8 afg = *(const bf16x8*)&Bs[(h * 48 + mt * 16 + lr) * 40 + lq * 8];
        f32x4 a0 = mfma16(afg, bf0, z);
        f32x4 a1 = mfma16(afg, bf1, z);
        for (int r = 0; r < 4; r++) {
          int c = h * 48 + mt * 16 + lq * 4 + r;
          bufA[(q * 32 + lr) * 392 + c]      = f2b(a0[r]);
          bufA[(q * 32 + 16 + lr) * 392 + c] = f2b(a1[r]);
        }
      }
    }
    __syncthreads();
  }

  gemm128(Wo_w_b, bufA, acc, wm, wn, lq, lr);
  {
    const float* s1p = scal + 1 * 24576 + b * 384;
    const float* s0p = scal + 0 * 24576 + b * 384;
#pragma unroll
    for (int nt = 0; nt < 6; nt++) {
      int col = wn * 96 + nt * 16 + lr;
      float r = s1p[col] / fmaxf(s0p[col], 1e-30f);
#pragma unroll
      for (int mt = 0; mt < 4; mt++)
#pragma unroll
        for (int rr = 0; rr < 4; rr++) acc[mt][nt][rr] *= r;
    }
  }
  __syncthreads();

  for (int i = tid; i < 6144; i += 512) {
    int row = i / 48, u8 = (i % 48) * 8;
    *(uint4*)&bufA[row * 392 + u8] = *(const uint4*)(y_h + (long)(m0 + row) * 384 + u8);
  }
  __syncthreads();
  gemm128(Wo_h_b, bufA, acc, wm, wn, lq, lr);
  __syncthreads();

  {
    const float* s0p = scal + 0 * 24576 + b * 384;
    const float* s1p = scal + 1 * 24576 + b * 384;
#pragma unroll
    for (int nt = 0; nt < 6; nt++) {
      int col = wn * 96 + nt * 16 + lr;
      float s0v = s0p[col];
      float bcb = s0v * bo_h[col] + s1p[col] * bo_w[col];
#pragma unroll
      for (int mt = 0; mt < 4; mt++)
#pragma unroll
        for (int r = 0; r < 4; r++) {
          int row = wm * 64 + mt * 16 + lq * 4 + r;
          bufA[row * 392 + col] = f2b(acc[mt][nt][r] * s0v + bcb);
        }
    }
  }
  __syncthreads();

#pragma unroll
  for (int i = 0; i < 4; i++)
#pragma unroll
    for (int jn = 0; jn < 6; jn++) acc[i][jn] = z;
  gemm128(Wp_b, bufA, acc, wm, wn, lq, lr);
#pragma unroll
  for (int nt = 0; nt < 6; nt++) {
    int col = wn * 96 + nt * 16 + lr;
    float bi = bp[col];
#pragma unroll
    for (int mt = 0; mt < 4; mt++)
#pragma unroll
      for (int r = 0; r < 4; r++) {
        int row = m0 + wm * 64 + mt * 16 + lq * 4 + r;
        out[(long)row * 384 + col] = acc[mt][nt][r] + bi;
      }
  }
}

// ---------------- host ----------------
extern "C" void kernel_launch(void* const* d_in, const int* in_sizes, int n_in,
                              void* d_out, int out_size, void* d_ws, size_t ws_size,
                              hipStream_t stream) {
  const float* x     = (const float*)d_in[0];
  const float* Wc_h  = (const float*)d_in[1];
  const float* bc_h  = (const float*)d_in[2];
  const float* Wg_h  = (const float*)d_in[3];
  const float* bg_h  = (const float*)d_in[4];
  const float* Wo_h  = (const float*)d_in[5];
  const float* bo_h  = (const float*)d_in[6];
  const float* Wc_w  = (const float*)d_in[7];
  const float* bc_w  = (const float*)d_in[8];
  const float* Wg_w  = (const float*)d_in[9];
  const float* bg_w  = (const float*)d_in[10];
  const float* Wo_w  = (const float*)d_in[11];
  const float* bo_w  = (const float*)d_in[12];
  const float* Wmlpc = (const float*)d_in[13];
  const float* Wr1   = (const float*)d_in[14];
  const float* br1   = (const float*)d_in[15];
  const float* Wr2   = (const float*)d_in[16];
  const float* br2   = (const float*)d_in[17];
  const float* Wp    = (const float*)d_in[18];
  const float* bp    = (const float*)d_in[19];
  float* out = (float*)d_out;

  // workspace layout: 61,530,112 bytes total (~58.7 MB)
  char* ws = (char*)d_ws;
  u16* y_h       = (u16*)(ws + 0);          // 50,331,648
  float* psum_yh = (float*)(ws + 50331648); //  3,145,728
  float* psum_yw = (float*)(ws + 53477376); //  3,145,728
  float* psum_x  = (float*)(ws + 56623104); //  3,145,728
  float* scal    = (float*)(ws + 59768832); //    294,912
  u16* Wc_h_b    = (u16*)(ws + 60063744);
  u16* Wc_w_b    = (u16*)(ws + 60076032);
  u16* Wg_h_b    = (u16*)(ws + 60088320);
  u16* Wg_w_b    = (u16*)(ws + 60219392);
  u16* Wo_h_b    = (u16*)(ws + 60350464);
  u16* Wo_w_b    = (u16*)(ws + 60645376);
  u16* Wmlpc_b   = (u16*)(ws + 60940288);
  u16* Wp_b      = (u16*)(ws + 61235200);

  CvtJobs jobs;
  jobs.s[0] = Wc_h;  jobs.d[0] = Wc_h_b;  jobs.n[0] = 6144;
  jobs.s[1] = Wc_w;  jobs.d[1] = Wc_w_b;  jobs.n[1] = 6144;
  jobs.s[2] = Wg_h;  jobs.d[2] = Wg_h_b;  jobs.n[2] = 65536;
  jobs.s[3] = Wg_w;  jobs.d[3] = Wg_w_b;  jobs.n[3] = 65536;
  jobs.s[4] = Wo_h;  jobs.d[4] = Wo_h_b;  jobs.n[4] = 147456;
  jobs.s[5] = Wo_w;  jobs.d[5] = Wo_w_b;  jobs.n[5] = 147456;
  jobs.s[6] = Wmlpc; jobs.d[6] = Wmlpc_b; jobs.n[6] = 147456;
  jobs.s[7] = Wp;    jobs.d[7] = Wp_b;    jobs.n[7] = 147456;
  k0_cvt<<<dim3(144, 8), 256, 0, stream>>>(jobs);

  k1_mixer<<<4096, 256, 0, stream>>>(x, Wc_h_b, bc_h, Wg_h_b, bg_h,
      Wc_w_b, bc_w, Wg_w_b, bg_w, y_h, psum_yh, psum_yw, psum_x);

  k3_scales<<<64, 384, 0, stream>>>(psum_yh, psum_yw, psum_x, Wo_h, bo_h,
      Wo_w, bo_w, Wmlpc, Wr1, br1, Wr2, br2, scal);

  k24_final<<<512, 512, 0, stream>>>(x, y_h, Wc_w_b, bc_w, Wg_w_b, bg_w,
      Wo_h_b, Wo_w_b, Wmlpc_b, Wp_b, bo_h, bo_w, bp, scal, out);
}